// Round 1
// baseline (831.872 us; speedup 1.0000x reference)
//
#include <hip/hip_runtime.h>
#include <hip/hip_bf16.h>
#include <math.h>

#define N_NODES 50000
#define F_IN    500
#define HEADS   8
#define HID     16
#define HH      128   // HEADS*HID
#define NCLS    40
#define NEG     0.2f

__device__ __forceinline__ float lrelu(float x) { return x >= 0.f ? x : NEG * x; }

__device__ __forceinline__ float sel4(float a, float b, float c, float d, int i) {
    // register-resident 4-way select (avoid dynamic indexing -> scratch)
    float r = a;
    r = (i == 1) ? b : r;
    r = (i == 2) ? c : r;
    r = (i == 3) ? d : r;
    return r;
}

// ---------------- GEMM1: h1[N,128] = x[N,500] @ W1[500,128] ----------------
__global__ __launch_bounds__(256) void gemm1_kernel(const float* __restrict__ x,
                                                    const float* __restrict__ W,
                                                    float* __restrict__ h1) {
    __shared__ float xs[16][F_IN];
    const int t = threadIdx.x;
    const int rowBase = blockIdx.x * 16;   // 50000 = 16*3125, exact
    for (int i = t; i < 16 * F_IN; i += 256) {
        int r = i / F_IN, k = i - r * F_IN;
        xs[r][k] = x[(size_t)(rowBase + r) * F_IN + k];
    }
    __syncthreads();
    const int cg = t & 31, rg = t >> 5;
    const int c0 = cg * 4, r0 = rg * 2;
    float acc[2][4] = {};
    for (int k = 0; k < F_IN; k += 4) {
        float4 w0 = *(const float4*)&W[(k + 0) * HH + c0];
        float4 w1 = *(const float4*)&W[(k + 1) * HH + c0];
        float4 w2 = *(const float4*)&W[(k + 2) * HH + c0];
        float4 w3 = *(const float4*)&W[(k + 3) * HH + c0];
#pragma unroll
        for (int r = 0; r < 2; ++r) {
            float4 xv = *(const float4*)&xs[r0 + r][k];
            acc[r][0] += xv.x * w0.x + xv.y * w1.x + xv.z * w2.x + xv.w * w3.x;
            acc[r][1] += xv.x * w0.y + xv.y * w1.y + xv.z * w2.y + xv.w * w3.y;
            acc[r][2] += xv.x * w0.z + xv.y * w1.z + xv.z * w2.z + xv.w * w3.z;
            acc[r][3] += xv.x * w0.w + xv.y * w1.w + xv.z * w2.w + xv.w * w3.w;
        }
    }
#pragma unroll
    for (int r = 0; r < 2; ++r) {
        float4 v = make_float4(acc[r][0], acc[r][1], acc[r][2], acc[r][3]);
        *(float4*)&h1[(size_t)(rowBase + r0 + r) * HH + c0] = v;
    }
}

// ---------------- per-node attention coefficients, layer 1 ----------------
__global__ void alpha1_kernel(const float* __restrict__ h1,
                              const float* __restrict__ a_src,
                              const float* __restrict__ a_dst,
                              float* __restrict__ asrc, float* __restrict__ adst) {
    int idx = blockIdx.x * blockDim.x + threadIdx.x;
    if (idx >= N_NODES * HEADS) return;
    int n = idx >> 3, h = idx & 7;
    const float4* hp = (const float4*)&h1[(size_t)n * HH + h * HID];
    const float4* sp = (const float4*)&a_src[h * HID];
    const float4* dp = (const float4*)&a_dst[h * HID];
    float s = 0.f, d = 0.f;
#pragma unroll
    for (int i = 0; i < 4; i++) {
        float4 hv = hp[i], sv = sp[i], dv = dp[i];
        s += hv.x * sv.x + hv.y * sv.y + hv.z * sv.z + hv.w * sv.w;
        d += hv.x * dv.x + hv.y * dv.y + hv.z * dv.z + hv.w * dv.w;
    }
    asrc[idx] = s;
    adst[idx] = d;
}

// ---------------- CSR build ----------------
__global__ void zero_int_kernel(int* __restrict__ p, int n) {
    int i = blockIdx.x * blockDim.x + threadIdx.x;
    if (i < n) p[i] = 0;
}

__global__ void count_kernel(const int* __restrict__ ei, int* __restrict__ deg,
                             int E, int EP) {
    int e = blockIdx.x * blockDim.x + threadIdx.x;
    if (e >= EP) return;
    int dst = (e < E) ? ei[E + e] : (e - E);
    atomicAdd(&deg[dst], 1);
}

__global__ __launch_bounds__(1024) void scan_kernel(const int* __restrict__ deg,
                                                    int* __restrict__ offs,
                                                    int* __restrict__ cursor, int n) {
    __shared__ int part[1024];
    int tid = threadIdx.x;
    int chunk = (n + 1023) / 1024;
    int start = tid * chunk;
    int end = min(start + chunk, n);
    int s = 0;
    for (int i = start; i < end; i++) s += deg[i];
    part[tid] = s;
    __syncthreads();
    for (int off = 1; off < 1024; off <<= 1) {
        int v = 0;
        if (tid >= off) v = part[tid - off];
        __syncthreads();
        if (tid >= off) part[tid] += v;
        __syncthreads();
    }
    int base = (tid == 0) ? 0 : part[tid - 1];
    for (int i = start; i < end; i++) {
        offs[i] = base;
        cursor[i] = base;
        base += deg[i];
    }
    if (tid == 1023) offs[n] = base;
}

__global__ void fill_kernel(const int* __restrict__ ei, int* __restrict__ cursor,
                            int* __restrict__ bsrc, int E, int EP) {
    int e = blockIdx.x * blockDim.x + threadIdx.x;
    if (e >= EP) return;
    int src, dst;
    if (e < E) { src = ei[e]; dst = ei[E + e]; }
    else       { src = e - E; dst = e - E; }
    int slot = atomicAdd(&cursor[dst], 1);
    bsrc[slot] = src;
}

// ---------------- layer-1 aggregation: one wave per dst node ----------------
__global__ __launch_bounds__(256) void agg1_kernel(const float* __restrict__ h1,
                                                   const float* __restrict__ asrc,
                                                   const float* __restrict__ adst,
                                                   const int* __restrict__ offs,
                                                   const int* __restrict__ bsrc,
                                                   const float* __restrict__ b1,
                                                   float* __restrict__ h1b) {
    int lane = threadIdx.x & 63;
    int node = blockIdx.x * 4 + (threadIdx.x >> 6);
    if (node >= N_NODES) return;
    int beg = offs[node], end = offs[node + 1];

    float4 D0 = *(const float4*)(adst + node * 8);
    float4 D1 = *(const float4*)(adst + node * 8 + 4);
    float adh[8] = {D0.x, D0.y, D0.z, D0.w, D1.x, D1.y, D1.z, D1.w};

    float mx[8];
#pragma unroll
    for (int h = 0; h < 8; h++) mx[h] = -1e30f;
    for (int j = beg + lane; j < end; j += 64) {
        int src = bsrc[j];
        float4 A0 = *(const float4*)(asrc + src * 8);
        float4 A1 = *(const float4*)(asrc + src * 8 + 4);
        float sv[8] = {A0.x, A0.y, A0.z, A0.w, A1.x, A1.y, A1.z, A1.w};
#pragma unroll
        for (int h = 0; h < 8; h++) mx[h] = fmaxf(mx[h], lrelu(sv[h] + adh[h]));
    }
#pragma unroll
    for (int h = 0; h < 8; h++) {
#pragma unroll
        for (int o = 32; o; o >>= 1) mx[h] = fmaxf(mx[h], __shfl_xor(mx[h], o, 64));
    }

    float ds[8] = {0, 0, 0, 0, 0, 0, 0, 0};
    for (int j = beg + lane; j < end; j += 64) {
        int src = bsrc[j];
        float4 A0 = *(const float4*)(asrc + src * 8);
        float4 A1 = *(const float4*)(asrc + src * 8 + 4);
        float sv[8] = {A0.x, A0.y, A0.z, A0.w, A1.x, A1.y, A1.z, A1.w};
#pragma unroll
        for (int h = 0; h < 8; h++) ds[h] += __expf(lrelu(sv[h] + adh[h]) - mx[h]);
    }
#pragma unroll
    for (int h = 0; h < 8; h++) {
#pragma unroll
        for (int o = 32; o; o >>= 1) ds[h] += __shfl_xor(ds[h], o, 64);
    }
    float rd[8];
#pragma unroll
    for (int h = 0; h < 8; h++) rd[h] = 1.f / (ds[h] + 1e-16f);

    // channel-parallel accumulation: lane owns channels lane and lane+64
    int h0 = lane >> 4;          // head for channel `lane`   (0..3)
    // head for channel lane+64 is h0+4
    float ad0 = sel4(adh[0], adh[1], adh[2], adh[3], h0);
    float ad1 = sel4(adh[4], adh[5], adh[6], adh[7], h0);
    float m0  = sel4(mx[0], mx[1], mx[2], mx[3], h0);
    float m1  = sel4(mx[4], mx[5], mx[6], mx[7], h0);
    float r0  = sel4(rd[0], rd[1], rd[2], rd[3], h0);
    float r1  = sel4(rd[4], rd[5], rd[6], rd[7], h0);

    float acc0 = 0.f, acc1 = 0.f;
    for (int j = beg; j < end; ++j) {
        int src = bsrc[j];
        float w0 = __expf(lrelu(asrc[src * 8 + h0] + ad0) - m0) * r0;
        float w1 = __expf(lrelu(asrc[src * 8 + 4 + h0] + ad1) - m1) * r1;
        acc0 += w0 * h1[(size_t)src * HH + lane];
        acc1 += w1 * h1[(size_t)src * HH + 64 + lane];
    }
    float v0 = acc0 + b1[lane];
    float v1 = acc1 + b1[64 + lane];
    v0 = v0 > 0.f ? v0 : __expf(v0) - 1.f;   // ELU
    v1 = v1 > 0.f ? v1 : __expf(v1) - 1.f;
    h1b[(size_t)node * HH + lane] = v0;
    h1b[(size_t)node * HH + 64 + lane] = v1;
}

// ---------------- GEMM2: h2[N,40] = h1b[N,128] @ W2[128,40] ----------------
__global__ __launch_bounds__(256) void gemm2_kernel(const float* __restrict__ h1b,
                                                    const float* __restrict__ W2,
                                                    float* __restrict__ h2) {
    __shared__ float Ws[HH * NCLS];
    for (int i = threadIdx.x; i < HH * NCLS; i += 256) Ws[i] = W2[i];
    __syncthreads();
    int idx = blockIdx.x * 256 + threadIdx.x;
    if (idx >= N_NODES * NCLS) return;
    int n = idx / NCLS, c = idx - n * NCLS;
    const float4* hp = (const float4*)&h1b[(size_t)n * HH];
    float acc = 0.f;
#pragma unroll
    for (int k4 = 0; k4 < HH / 4; ++k4) {
        float4 hv = hp[k4];
        int k = k4 * 4;
        acc += hv.x * Ws[k * NCLS + c] + hv.y * Ws[(k + 1) * NCLS + c] +
               hv.z * Ws[(k + 2) * NCLS + c] + hv.w * Ws[(k + 3) * NCLS + c];
    }
    h2[idx] = acc;
}

__global__ void alpha2_kernel(const float* __restrict__ h2,
                              const float* __restrict__ a_src,
                              const float* __restrict__ a_dst,
                              float* __restrict__ asrc, float* __restrict__ adst) {
    int n = blockIdx.x * blockDim.x + threadIdx.x;
    if (n >= N_NODES) return;
    float s = 0.f, d = 0.f;
#pragma unroll
    for (int i = 0; i < NCLS; i++) {
        float hv = h2[(size_t)n * NCLS + i];
        s += hv * a_src[i];
        d += hv * a_dst[i];
    }
    asrc[n] = s;
    adst[n] = d;
}

// ---------------- layer-2 aggregation (1 head, 40 channels) ----------------
__global__ __launch_bounds__(256) void agg2_kernel(const float* __restrict__ h2,
                                                   const float* __restrict__ asrc,
                                                   const float* __restrict__ adst,
                                                   const int* __restrict__ offs,
                                                   const int* __restrict__ bsrc,
                                                   const float* __restrict__ b2,
                                                   float* __restrict__ out) {
    int lane = threadIdx.x & 63;
    int node = blockIdx.x * 4 + (threadIdx.x >> 6);
    if (node >= N_NODES) return;
    int beg = offs[node], end = offs[node + 1];
    float adv = adst[node];
    float mx = -1e30f;
    for (int j = beg + lane; j < end; j += 64)
        mx = fmaxf(mx, lrelu(asrc[bsrc[j]] + adv));
#pragma unroll
    for (int o = 32; o; o >>= 1) mx = fmaxf(mx, __shfl_xor(mx, o, 64));
    float ds = 0.f;
    for (int j = beg + lane; j < end; j += 64)
        ds += __expf(lrelu(asrc[bsrc[j]] + adv) - mx);
#pragma unroll
    for (int o = 32; o; o >>= 1) ds += __shfl_xor(ds, o, 64);
    float rd = 1.f / (ds + 1e-16f);
    float acc = 0.f;
    for (int j = beg; j < end; ++j) {
        int src = bsrc[j];
        float w = __expf(lrelu(asrc[src] + adv) - mx) * rd;
        if (lane < NCLS) acc += w * h2[(size_t)src * NCLS + lane];
    }
    if (lane < NCLS) out[(size_t)node * NCLS + lane] = acc + b2[lane];
}

// ---------------- log_softmax in place on d_out ----------------
__global__ __launch_bounds__(256) void logsoftmax_kernel(float* __restrict__ out) {
    int lane = threadIdx.x & 63;
    int node = blockIdx.x * 4 + (threadIdx.x >> 6);
    if (node >= N_NODES) return;
    float v = (lane < NCLS) ? out[(size_t)node * NCLS + lane] : -1e30f;
    float m = v;
#pragma unroll
    for (int o = 32; o; o >>= 1) m = fmaxf(m, __shfl_xor(m, o, 64));
    float p = (lane < NCLS) ? __expf(v - m) : 0.f;
    float s = p;
#pragma unroll
    for (int o = 32; o; o >>= 1) s += __shfl_xor(s, o, 64);
    float ls = m + __logf(s);
    if (lane < NCLS) out[(size_t)node * NCLS + lane] = v - ls;
}

extern "C" void kernel_launch(void* const* d_in, const int* in_sizes, int n_in,
                              void* d_out, int out_size, void* d_ws, size_t ws_size,
                              hipStream_t stream) {
    const float* x      = (const float*)d_in[0];
    const int*   ei     = (const int*)d_in[1];
    const float* W1     = (const float*)d_in[2];
    const float* a_src1 = (const float*)d_in[3];
    const float* a_dst1 = (const float*)d_in[4];
    const float* b1     = (const float*)d_in[5];
    const float* W2     = (const float*)d_in[6];
    const float* a_src2 = (const float*)d_in[7];
    const float* a_dst2 = (const float*)d_in[8];
    const float* b2     = (const float*)d_in[9];
    float* out = (float*)d_out;

    const int E  = in_sizes[1] / 2;
    const int EP = E + N_NODES;

    char* w = (char*)d_ws;
    float* h1    = (float*)(w + 0);          // 25,600,000 B
    float* h1b   = (float*)(w + 25600000);   // 25,600,000 B
    float* asrc1 = (float*)(w + 51200000);   //  1,600,000 B
    float* adst1 = (float*)(w + 52800000);   //  1,600,000 B
    float* h2    = (float*)(w + 54400000);   //  8,000,000 B
    float* asrc2 = (float*)(w + 62400000);   //    200,000 B
    float* adst2 = (float*)(w + 62600000);   //    200,000 B
    int*   deg   = (int*)(w + 62800000);     //    200,000 B
    int*   offs  = (int*)(w + 63000064);     //    200,004 B
    int*   cursor= (int*)(w + 63300096);     //    200,000 B
    int*   bsrc  = (int*)(w + 63600128);     //  3,400,000 B  (end ~67.0 MB)

    zero_int_kernel<<<(N_NODES + 255) / 256, 256, 0, stream>>>(deg, N_NODES);
    gemm1_kernel<<<N_NODES / 16, 256, 0, stream>>>(x, W1, h1);
    alpha1_kernel<<<(N_NODES * HEADS + 255) / 256, 256, 0, stream>>>(h1, a_src1, a_dst1,
                                                                     asrc1, adst1);
    count_kernel<<<(EP + 255) / 256, 256, 0, stream>>>(ei, deg, E, EP);
    scan_kernel<<<1, 1024, 0, stream>>>(deg, offs, cursor, N_NODES);
    fill_kernel<<<(EP + 255) / 256, 256, 0, stream>>>(ei, cursor, bsrc, E, EP);
    agg1_kernel<<<(N_NODES + 3) / 4, 256, 0, stream>>>(h1, asrc1, adst1, offs, bsrc, b1, h1b);
    gemm2_kernel<<<(N_NODES * NCLS + 255) / 256, 256, 0, stream>>>(h1b, W2, h2);
    alpha2_kernel<<<(N_NODES + 255) / 256, 256, 0, stream>>>(h2, a_src2, a_dst2,
                                                             asrc2, adst2);
    agg2_kernel<<<(N_NODES + 3) / 4, 256, 0, stream>>>(h2, asrc2, adst2, offs, bsrc, b2, out);
    logsoftmax_kernel<<<(N_NODES + 3) / 4, 256, 0, stream>>>(out);
}

// Round 4
// 668.956 us; speedup vs baseline: 1.2435x; 1.2435x over previous
//
#include <hip/hip_runtime.h>
#include <hip/hip_bf16.h>
#include <math.h>

#define N_NODES 50000
#define F_IN    500
#define HEADS   8
#define HID     16
#define HH      128   // HEADS*HID
#define NCLS    40
#define NEG     0.2f

typedef _Float16 f16x4 __attribute__((ext_vector_type(4)));
typedef _Float16 f16x8 __attribute__((ext_vector_type(8)));
typedef float    f32x4 __attribute__((ext_vector_type(4)));

__device__ __forceinline__ float lrelu(float x) { return x >= 0.f ? x : NEG * x; }

__device__ __forceinline__ float sel4(float a, float b, float c, float d, int i) {
    float r = a;
    r = (i == 1) ? b : r;
    r = (i == 2) ? c : r;
    r = (i == 3) ? d : r;
    return r;
}

// -------- convert W1[500][128] -> Wt[128][512] fp16, K zero-padded --------
__global__ void convW_kernel(const float* __restrict__ W1, _Float16* __restrict__ Wt) {
    int i = blockIdx.x * 256 + threadIdx.x;
    if (i >= 128 * 512) return;
    int c = i >> 9, k = i & 511;
    Wt[i] = (k < F_IN) ? (_Float16)W1[k * HH + c] : (_Float16)0.f;
}

// ---------------- GEMM1 (MFMA fp16): h1[N,128] = x[N,500] @ W1 ----------------
// 64 rows x 128 cols per block, K-tile 128, 4 waves (16 rows each).
#define KT   128
#define LDP  136   // padded LDS row stride (halves): 272 B -> 2-way bank alias (free)
__global__ __launch_bounds__(256) void gemm1_mfma(const float* __restrict__ x,
                                                  const _Float16* __restrict__ Wt,
                                                  float* __restrict__ h1) {
    __shared__ _Float16 As[64 * LDP];
    __shared__ _Float16 Bs[128 * LDP];
    const int t = threadIdx.x;
    const int lane = t & 63, w = t >> 6;
    const int rowBase = blockIdx.x * 64;

    f32x4 acc[8];
#pragma unroll
    for (int n = 0; n < 8; ++n) acc[n] = (f32x4){0.f, 0.f, 0.f, 0.f};

    const int fa = t & 31, ra = t >> 5;   // A staging: float4 idx, row group
    const int gb = t & 15, cb = t >> 4;   // B staging: 8-half idx, col group

    for (int kt = 0; kt < 4; ++kt) {
        const int kt0 = kt * KT;
        // stage A: x fp32 -> fp16 LDS (fused cast), zero-pad tail
#pragma unroll
        for (int p = 0; p < 8; ++p) {
            int row = ra + 8 * p;
            int grow = rowBase + row;
            int k0 = kt0 + 4 * fa;
            float4 v = make_float4(0.f, 0.f, 0.f, 0.f);
            if (grow < N_NODES && k0 < F_IN)
                v = *(const float4*)&x[(size_t)grow * F_IN + k0];
            f16x4 hv = {(_Float16)v.x, (_Float16)v.y, (_Float16)v.z, (_Float16)v.w};
            *(f16x4*)&As[row * LDP + 4 * fa] = hv;
        }
        // stage B from pre-converted Wt (contiguous 16B copies)
#pragma unroll
        for (int p = 0; p < 8; ++p) {
            int c = cb + 16 * p;
            *(f16x8*)&Bs[c * LDP + 8 * gb] = *(const f16x8*)&Wt[c * 512 + kt0 + 8 * gb];
        }
        __syncthreads();
#pragma unroll
        for (int ks = 0; ks < 4; ++ks) {
            int kk = ks * 32 + (lane >> 4) * 8;
            f16x8 a = *(const f16x8*)&As[(16 * w + (lane & 15)) * LDP + kk];
#pragma unroll
            for (int n = 0; n < 8; ++n) {
                f16x8 b = *(const f16x8*)&Bs[(16 * n + (lane & 15)) * LDP + kk];
                acc[n] = __builtin_amdgcn_mfma_f32_16x16x32_f16(a, b, acc[n], 0, 0, 0);
            }
        }
        __syncthreads();
    }
    // epilogue: D layout col=lane&15, row=(lane>>4)*4+reg
    const int colb = lane & 15, rq = lane >> 4;
#pragma unroll
    for (int n = 0; n < 8; ++n) {
#pragma unroll
        for (int r = 0; r < 4; ++r) {
            int grow = rowBase + 16 * w + rq * 4 + r;
            if (grow < N_NODES) h1[(size_t)grow * HH + 16 * n + colb] = acc[n][r];
        }
    }
}

// ---------------- per-node attention coefficients, layer 1 ----------------
__global__ void alpha1_kernel(const float* __restrict__ h1,
                              const float* __restrict__ a_src,
                              const float* __restrict__ a_dst,
                              float* __restrict__ asrc, float* __restrict__ adst) {
    int idx = blockIdx.x * blockDim.x + threadIdx.x;
    if (idx >= N_NODES * HEADS) return;
    int n = idx >> 3, h = idx & 7;
    const float4* hp = (const float4*)&h1[(size_t)n * HH + h * HID];
    const float4* sp = (const float4*)&a_src[h * HID];
    const float4* dp = (const float4*)&a_dst[h * HID];
    float s = 0.f, d = 0.f;
#pragma unroll
    for (int i = 0; i < 4; i++) {
        float4 hv = hp[i], sv = sp[i], dv = dp[i];
        s += hv.x * sv.x + hv.y * sv.y + hv.z * sv.z + hv.w * sv.w;
        d += hv.x * dv.x + hv.y * dv.y + hv.z * dv.z + hv.w * dv.w;
    }
    asrc[idx] = s;
    adst[idx] = d;
}

// ---------------- CSR build ----------------
__global__ void zero_int_kernel(int* __restrict__ p, int n) {
    int i = blockIdx.x * blockDim.x + threadIdx.x;
    if (i < n) p[i] = 0;
}

__global__ void count_kernel(const int* __restrict__ ei, int* __restrict__ deg,
                             int E, int EP) {
    int e = blockIdx.x * blockDim.x + threadIdx.x;
    if (e >= EP) return;
    int dst = (e < E) ? ei[E + e] : (e - E);
    atomicAdd(&deg[dst], 1);
}

__global__ __launch_bounds__(1024) void scan_kernel(const int* __restrict__ deg,
                                                    int* __restrict__ offs,
                                                    int* __restrict__ cursor, int n) {
    __shared__ int part[1024];
    int tid = threadIdx.x;
    int chunk = (n + 1023) / 1024;
    int start = tid * chunk;
    int end = min(start + chunk, n);
    int s = 0;
    for (int i = start; i < end; i++) s += deg[i];
    part[tid] = s;
    __syncthreads();
    for (int off = 1; off < 1024; off <<= 1) {
        int v = 0;
        if (tid >= off) v = part[tid - off];
        __syncthreads();
        if (tid >= off) part[tid] += v;
        __syncthreads();
    }
    int base = (tid == 0) ? 0 : part[tid - 1];
    for (int i = start; i < end; i++) {
        offs[i] = base;
        cursor[i] = base;
        base += deg[i];
    }
    if (tid == 1023) offs[n] = base;
}

__global__ void fill_kernel(const int* __restrict__ ei, int* __restrict__ cursor,
                            int* __restrict__ bsrc, int E, int EP) {
    int e = blockIdx.x * blockDim.x + threadIdx.x;
    if (e >= EP) return;
    int src, dst;
    if (e < E) { src = ei[e]; dst = ei[E + e]; }
    else       { src = e - E; dst = e - E; }
    int slot = atomicAdd(&cursor[dst], 1);
    bsrc[slot] = src;
}

// ---------------- layer-1 aggregation: one wave per dst node ----------------
__global__ __launch_bounds__(256) void agg1_kernel(const float* __restrict__ h1,
                                                   const float* __restrict__ asrc,
                                                   const float* __restrict__ adst,
                                                   const int* __restrict__ offs,
                                                   const int* __restrict__ bsrc,
                                                   const float* __restrict__ b1,
                                                   float* __restrict__ h1b) {
    int lane = threadIdx.x & 63;
    int node = blockIdx.x * 4 + (threadIdx.x >> 6);
    if (node >= N_NODES) return;
    int beg = offs[node], end = offs[node + 1];

    float4 D0 = *(const float4*)(adst + node * 8);
    float4 D1 = *(const float4*)(adst + node * 8 + 4);
    float adh[8] = {D0.x, D0.y, D0.z, D0.w, D1.x, D1.y, D1.z, D1.w};

    float mx[8];
#pragma unroll
    for (int h = 0; h < 8; h++) mx[h] = -1e30f;
    for (int j = beg + lane; j < end; j += 64) {
        int src = bsrc[j];
        float4 A0 = *(const float4*)(asrc + src * 8);
        float4 A1 = *(const float4*)(asrc + src * 8 + 4);
        float sv[8] = {A0.x, A0.y, A0.z, A0.w, A1.x, A1.y, A1.z, A1.w};
#pragma unroll
        for (int h = 0; h < 8; h++) mx[h] = fmaxf(mx[h], lrelu(sv[h] + adh[h]));
    }
#pragma unroll
    for (int h = 0; h < 8; h++) {
#pragma unroll
        for (int o = 32; o; o >>= 1) mx[h] = fmaxf(mx[h], __shfl_xor(mx[h], o, 64));
    }

    float ds[8] = {0, 0, 0, 0, 0, 0, 0, 0};
    for (int j = beg + lane; j < end; j += 64) {
        int src = bsrc[j];
        float4 A0 = *(const float4*)(asrc + src * 8);
        float4 A1 = *(const float4*)(asrc + src * 8 + 4);
        float sv[8] = {A0.x, A0.y, A0.z, A0.w, A1.x, A1.y, A1.z, A1.w};
#pragma unroll
        for (int h = 0; h < 8; h++) ds[h] += __expf(lrelu(sv[h] + adh[h]) - mx[h]);
    }
#pragma unroll
    for (int h = 0; h < 8; h++) {
#pragma unroll
        for (int o = 32; o; o >>= 1) ds[h] += __shfl_xor(ds[h], o, 64);
    }
    float rd[8];
#pragma unroll
    for (int h = 0; h < 8; h++) rd[h] = 1.f / (ds[h] + 1e-16f);

    int h0 = lane >> 4;
    float ad0 = sel4(adh[0], adh[1], adh[2], adh[3], h0);
    float ad1 = sel4(adh[4], adh[5], adh[6], adh[7], h0);
    float m0  = sel4(mx[0], mx[1], mx[2], mx[3], h0);
    float m1  = sel4(mx[4], mx[5], mx[6], mx[7], h0);
    float r0  = sel4(rd[0], rd[1], rd[2], rd[3], h0);
    float r1  = sel4(rd[4], rd[5], rd[6], rd[7], h0);

    float acc0 = 0.f, acc1 = 0.f;
    for (int j = beg; j < end; ++j) {
        int src = bsrc[j];
        float w0 = __expf(lrelu(asrc[src * 8 + h0] + ad0) - m0) * r0;
        float w1 = __expf(lrelu(asrc[src * 8 + 4 + h0] + ad1) - m1) * r1;
        acc0 += w0 * h1[(size_t)src * HH + lane];
        acc1 += w1 * h1[(size_t)src * HH + 64 + lane];
    }
    float v0 = acc0 + b1[lane];
    float v1 = acc1 + b1[64 + lane];
    v0 = v0 > 0.f ? v0 : __expf(v0) - 1.f;
    v1 = v1 > 0.f ? v1 : __expf(v1) - 1.f;
    h1b[(size_t)node * HH + lane] = v0;
    h1b[(size_t)node * HH + 64 + lane] = v1;
}

// ---------------- GEMM2: h2[N,40] = h1b[N,128] @ W2[128,40] ----------------
__global__ __launch_bounds__(256) void gemm2_kernel(const float* __restrict__ h1b,
                                                    const float* __restrict__ W2,
                                                    float* __restrict__ h2) {
    __shared__ float Ws[HH * NCLS];
    for (int i = threadIdx.x; i < HH * NCLS; i += 256) Ws[i] = W2[i];
    __syncthreads();
    int idx = blockIdx.x * 256 + threadIdx.x;
    if (idx >= N_NODES * NCLS) return;
    int n = idx / NCLS, c = idx - n * NCLS;
    const float4* hp = (const float4*)&h1b[(size_t)n * HH];
    float acc = 0.f;
#pragma unroll
    for (int k4 = 0; k4 < HH / 4; ++k4) {
        float4 hv = hp[k4];
        int k = k4 * 4;
        acc += hv.x * Ws[k * NCLS + c] + hv.y * Ws[(k + 1) * NCLS + c] +
               hv.z * Ws[(k + 2) * NCLS + c] + hv.w * Ws[(k + 3) * NCLS + c];
    }
    h2[idx] = acc;
}

__global__ void alpha2_kernel(const float* __restrict__ h2,
                              const float* __restrict__ a_src,
                              const float* __restrict__ a_dst,
                              float* __restrict__ asrc, float* __restrict__ adst) {
    int n = blockIdx.x * blockDim.x + threadIdx.x;
    if (n >= N_NODES) return;
    float s = 0.f, d = 0.f;
#pragma unroll
    for (int i = 0; i < NCLS; i++) {
        float hv = h2[(size_t)n * NCLS + i];
        s += hv * a_src[i];
        d += hv * a_dst[i];
    }
    asrc[n] = s;
    adst[n] = d;
}

// ---------------- layer-2 aggregation (1 head, 40 channels) ----------------
__global__ __launch_bounds__(256) void agg2_kernel(const float* __restrict__ h2,
                                                   const float* __restrict__ asrc,
                                                   const float* __restrict__ adst,
                                                   const int* __restrict__ offs,
                                                   const int* __restrict__ bsrc,
                                                   const float* __restrict__ b2,
                                                   float* __restrict__ out) {
    int lane = threadIdx.x & 63;
    int node = blockIdx.x * 4 + (threadIdx.x >> 6);
    if (node >= N_NODES) return;
    int beg = offs[node], end = offs[node + 1];
    float adv = adst[node];
    float mx = -1e30f;
    for (int j = beg + lane; j < end; j += 64)
        mx = fmaxf(mx, lrelu(asrc[bsrc[j]] + adv));
#pragma unroll
    for (int o = 32; o; o >>= 1) mx = fmaxf(mx, __shfl_xor(mx, o, 64));
    float ds = 0.f;
    for (int j = beg + lane; j < end; j += 64)
        ds += __expf(lrelu(asrc[bsrc[j]] + adv) - mx);
#pragma unroll
    for (int o = 32; o; o >>= 1) ds += __shfl_xor(ds, o, 64);
    float rd = 1.f / (ds + 1e-16f);
    float acc = 0.f;
    for (int j = beg; j < end; ++j) {
        int src = bsrc[j];
        float w = __expf(lrelu(asrc[src] + adv) - mx) * rd;
        if (lane < NCLS) acc += w * h2[(size_t)src * NCLS + lane];
    }
    if (lane < NCLS) out[(size_t)node * NCLS + lane] = acc + b2[lane];
}

// ---------------- log_softmax in place on d_out ----------------
__global__ __launch_bounds__(256) void logsoftmax_kernel(float* __restrict__ out) {
    int lane = threadIdx.x & 63;
    int node = blockIdx.x * 4 + (threadIdx.x >> 6);
    if (node >= N_NODES) return;
    float v = (lane < NCLS) ? out[(size_t)node * NCLS + lane] : -1e30f;
    float m = v;
#pragma unroll
    for (int o = 32; o; o >>= 1) m = fmaxf(m, __shfl_xor(m, o, 64));
    float p = (lane < NCLS) ? __expf(v - m) : 0.f;
    float s = p;
#pragma unroll
    for (int o = 32; o; o >>= 1) s += __shfl_xor(s, o, 64);
    float ls = m + __logf(s);
    if (lane < NCLS) out[(size_t)node * NCLS + lane] = v - ls;
}

extern "C" void kernel_launch(void* const* d_in, const int* in_sizes, int n_in,
                              void* d_out, int out_size, void* d_ws, size_t ws_size,
                              hipStream_t stream) {
    const float* x      = (const float*)d_in[0];
    const int*   ei     = (const int*)d_in[1];
    const float* W1     = (const float*)d_in[2];
    const float* a_src1 = (const float*)d_in[3];
    const float* a_dst1 = (const float*)d_in[4];
    const float* b1     = (const float*)d_in[5];
    const float* W2     = (const float*)d_in[6];
    const float* a_src2 = (const float*)d_in[7];
    const float* a_dst2 = (const float*)d_in[8];
    const float* b2     = (const float*)d_in[9];
    float* out = (float*)d_out;

    const int E  = in_sizes[1] / 2;
    const int EP = E + N_NODES;

    char* w = (char*)d_ws;
    float*     h1    = (float*)(w + 0);          // 25,600,000 B
    float*     h1b   = (float*)(w + 25600000);   // 25,600,000 B
    float*     asrc1 = (float*)(w + 51200000);   //  1,600,000 B
    float*     adst1 = (float*)(w + 52800000);   //  1,600,000 B
    float*     h2    = (float*)(w + 54400000);   //  8,000,000 B
    float*     asrc2 = (float*)(w + 62400000);   //    200,000 B
    float*     adst2 = (float*)(w + 62600000);   //    200,000 B
    int*       deg   = (int*)(w + 62800000);     //    200,000 B
    int*       offs  = (int*)(w + 63000064);     //    200,004 B
    int*       cursor= (int*)(w + 63300096);     //    200,000 B
    int*       bsrc  = (int*)(w + 63600128);     //  3,400,000 B
    _Float16*  Wt    = (_Float16*)(w + 67000320);//    131,072 B (end ~67.1 MB)

    zero_int_kernel<<<(N_NODES + 255) / 256, 256, 0, stream>>>(deg, N_NODES);
    convW_kernel<<<(128 * 512 + 255) / 256, 256, 0, stream>>>(W1, Wt);
    gemm1_mfma<<<(N_NODES + 63) / 64, 256, 0, stream>>>(x, Wt, h1);
    alpha1_kernel<<<(N_NODES * HEADS + 255) / 256, 256, 0, stream>>>(h1, a_src1, a_dst1,
                                                                     asrc1, adst1);
    count_kernel<<<(EP + 255) / 256, 256, 0, stream>>>(ei, deg, E, EP);
    scan_kernel<<<1, 1024, 0, stream>>>(deg, offs, cursor, N_NODES);
    fill_kernel<<<(EP + 255) / 256, 256, 0, stream>>>(ei, cursor, bsrc, E, EP);
    agg1_kernel<<<(N_NODES + 3) / 4, 256, 0, stream>>>(h1, asrc1, adst1, offs, bsrc, b1, h1b);
    gemm2_kernel<<<(N_NODES * NCLS + 255) / 256, 256, 0, stream>>>(h1b, W2, h2);
    alpha2_kernel<<<(N_NODES + 255) / 256, 256, 0, stream>>>(h2, a_src2, a_dst2,
                                                             asrc2, adst2);
    agg2_kernel<<<(N_NODES + 3) / 4, 256, 0, stream>>>(h2, asrc2, adst2, offs, bsrc, b2, out);
    logsoftmax_kernel<<<(N_NODES + 3) / 4, 256, 0, stream>>>(out);
}

// Round 5
// 642.747 us; speedup vs baseline: 1.2942x; 1.0408x over previous
//
#include <hip/hip_runtime.h>
#include <hip/hip_bf16.h>
#include <math.h>

#define N_NODES 50000
#define F_IN    500
#define HEADS   8
#define HID     16
#define HH      128   // HEADS*HID
#define NCLS    40
#define NEG     0.2f

typedef _Float16 f16x2 __attribute__((ext_vector_type(2)));
typedef _Float16 f16x4 __attribute__((ext_vector_type(4)));
typedef _Float16 f16x8 __attribute__((ext_vector_type(8)));
typedef float    f32x4 __attribute__((ext_vector_type(4)));

__device__ __forceinline__ float lrelu(float x) { return x >= 0.f ? x : NEG * x; }

__device__ __forceinline__ float sel4(float a, float b, float c, float d, int i) {
    float r = a;
    r = (i == 1) ? b : r;
    r = (i == 2) ? c : r;
    r = (i == 3) ? d : r;
    return r;
}
__device__ __forceinline__ float sel8(float a, float b, float c, float d,
                                      float e, float f, float g, float h, int i) {
    float lo = sel4(a, b, c, d, i & 3);
    float hi = sel4(e, f, g, h, i & 3);
    return (i & 4) ? hi : lo;
}

// -------- convert W1[500][128] -> Wt[128][512] fp16, K zero-padded --------
__global__ void convW_kernel(const float* __restrict__ W1, _Float16* __restrict__ Wt) {
    int i = blockIdx.x * 256 + threadIdx.x;
    if (i >= 128 * 512) return;
    int c = i >> 9, k = i & 511;
    Wt[i] = (k < F_IN) ? (_Float16)W1[k * HH + c] : (_Float16)0.f;
}

// ---------------- GEMM1 (MFMA fp16): h1h[N,128] = fp16(x[N,500] @ W1) ----------------
#define KT   128
#define LDP  136   // padded LDS row stride (halves)
__global__ __launch_bounds__(256) void gemm1_mfma(const float* __restrict__ x,
                                                  const _Float16* __restrict__ Wt,
                                                  _Float16* __restrict__ h1h) {
    __shared__ _Float16 As[64 * LDP];
    __shared__ _Float16 Bs[128 * LDP];
    const int t = threadIdx.x;
    const int lane = t & 63, w = t >> 6;
    const int rowBase = blockIdx.x * 64;

    f32x4 acc[8];
#pragma unroll
    for (int n = 0; n < 8; ++n) acc[n] = (f32x4){0.f, 0.f, 0.f, 0.f};

    const int fa = t & 31, ra = t >> 5;
    const int gb = t & 15, cb = t >> 4;

    for (int kt = 0; kt < 4; ++kt) {
        const int kt0 = kt * KT;
#pragma unroll
        for (int p = 0; p < 8; ++p) {
            int row = ra + 8 * p;
            int grow = rowBase + row;
            int k0 = kt0 + 4 * fa;
            float4 v = make_float4(0.f, 0.f, 0.f, 0.f);
            if (grow < N_NODES && k0 < F_IN)
                v = *(const float4*)&x[(size_t)grow * F_IN + k0];
            f16x4 hv = {(_Float16)v.x, (_Float16)v.y, (_Float16)v.z, (_Float16)v.w};
            *(f16x4*)&As[row * LDP + 4 * fa] = hv;
        }
#pragma unroll
        for (int p = 0; p < 8; ++p) {
            int c = cb + 16 * p;
            *(f16x8*)&Bs[c * LDP + 8 * gb] = *(const f16x8*)&Wt[c * 512 + kt0 + 8 * gb];
        }
        __syncthreads();
#pragma unroll
        for (int ks = 0; ks < 4; ++ks) {
            int kk = ks * 32 + (lane >> 4) * 8;
            f16x8 a = *(const f16x8*)&As[(16 * w + (lane & 15)) * LDP + kk];
#pragma unroll
            for (int n = 0; n < 8; ++n) {
                f16x8 b = *(const f16x8*)&Bs[(16 * n + (lane & 15)) * LDP + kk];
                acc[n] = __builtin_amdgcn_mfma_f32_16x16x32_f16(a, b, acc[n], 0, 0, 0);
            }
        }
        __syncthreads();
    }
    const int colb = lane & 15, rq = lane >> 4;
#pragma unroll
    for (int n = 0; n < 8; ++n) {
#pragma unroll
        for (int r = 0; r < 4; ++r) {
            int grow = rowBase + 16 * w + rq * 4 + r;
            if (grow < N_NODES) h1h[(size_t)grow * HH + 16 * n + colb] = (_Float16)acc[n][r];
        }
    }
}

// ---------------- per-node attention coefficients, layer 1 (fp16 h) ----------------
__global__ void alpha1_kernel(const _Float16* __restrict__ h1h,
                              const float* __restrict__ a_src,
                              const float* __restrict__ a_dst,
                              float* __restrict__ asrc, float* __restrict__ adst) {
    int idx = blockIdx.x * blockDim.x + threadIdx.x;
    if (idx >= N_NODES * HEADS) return;
    int n = idx >> 3, h = idx & 7;
    const f16x8* hp = (const f16x8*)&h1h[(size_t)n * HH + h * HID];
    float s = 0.f, d = 0.f;
#pragma unroll
    for (int c = 0; c < 2; ++c) {
        f16x8 hv = hp[c];
#pragma unroll
        for (int i = 0; i < 8; ++i) {
            float f = (float)hv[i];
            s += f * a_src[h * HID + c * 8 + i];
            d += f * a_dst[h * HID + c * 8 + i];
        }
    }
    asrc[idx] = s;
    adst[idx] = d;
}

// ---------------- CSR build ----------------
__global__ void zero_int_kernel(int* __restrict__ p, int n) {
    int i = blockIdx.x * blockDim.x + threadIdx.x;
    if (i < n) p[i] = 0;
}

__global__ void count_kernel(const int* __restrict__ ei, int* __restrict__ deg,
                             int E, int EP) {
    int e = blockIdx.x * blockDim.x + threadIdx.x;
    if (e >= EP) return;
    int dst = (e < E) ? ei[E + e] : (e - E);
    atomicAdd(&deg[dst], 1);
}

__global__ __launch_bounds__(1024) void scan_kernel(const int* __restrict__ deg,
                                                    int* __restrict__ offs,
                                                    int* __restrict__ cursor, int n) {
    __shared__ int part[1024];
    int tid = threadIdx.x;
    int chunk = (n + 1023) / 1024;
    int start = tid * chunk;
    int end = min(start + chunk, n);
    int s = 0;
    for (int i = start; i < end; i++) s += deg[i];
    part[tid] = s;
    __syncthreads();
    for (int off = 1; off < 1024; off <<= 1) {
        int v = 0;
        if (tid >= off) v = part[tid - off];
        __syncthreads();
        if (tid >= off) part[tid] += v;
        __syncthreads();
    }
    int base = (tid == 0) ? 0 : part[tid - 1];
    for (int i = start; i < end; i++) {
        offs[i] = base;
        cursor[i] = base;
        base += deg[i];
    }
    if (tid == 1023) offs[n] = base;
}

__global__ void fill_kernel(const int* __restrict__ ei, int* __restrict__ cursor,
                            int* __restrict__ bsrc, int E, int EP) {
    int e = blockIdx.x * blockDim.x + threadIdx.x;
    if (e >= EP) return;
    int src, dst;
    if (e < E) { src = ei[e]; dst = ei[E + e]; }
    else       { src = e - E; dst = e - E; }
    int slot = atomicAdd(&cursor[dst], 1);
    bsrc[slot] = src;
}

// ---------------- layer-1 aggregation: one wave per dst node ----------------
// lane owns channels 2l,2l+1 (head = l>>3): ONE f16x2 load per edge per lane.
__global__ __launch_bounds__(256) void agg1_kernel(const _Float16* __restrict__ h1h,
                                                   const float* __restrict__ asrc,
                                                   const float* __restrict__ adst,
                                                   const int* __restrict__ offs,
                                                   const int* __restrict__ bsrc,
                                                   const float* __restrict__ b1,
                                                   _Float16* __restrict__ h1bh) {
    int lane = threadIdx.x & 63;
    int node = blockIdx.x * 4 + (threadIdx.x >> 6);
    if (node >= N_NODES) return;
    int beg = offs[node], end = offs[node + 1];

    float4 D0 = *(const float4*)(adst + node * 8);
    float4 D1 = *(const float4*)(adst + node * 8 + 4);
    float adh[8] = {D0.x, D0.y, D0.z, D0.w, D1.x, D1.y, D1.z, D1.w};

    float mx[8];
#pragma unroll
    for (int h = 0; h < 8; h++) mx[h] = -1e30f;
    for (int j = beg + lane; j < end; j += 64) {
        int src = bsrc[j];
        float4 A0 = *(const float4*)(asrc + src * 8);
        float4 A1 = *(const float4*)(asrc + src * 8 + 4);
        float sv[8] = {A0.x, A0.y, A0.z, A0.w, A1.x, A1.y, A1.z, A1.w};
#pragma unroll
        for (int h = 0; h < 8; h++) mx[h] = fmaxf(mx[h], lrelu(sv[h] + adh[h]));
    }
#pragma unroll
    for (int h = 0; h < 8; h++) {
#pragma unroll
        for (int o = 32; o; o >>= 1) mx[h] = fmaxf(mx[h], __shfl_xor(mx[h], o, 64));
    }

    float ds[8] = {0, 0, 0, 0, 0, 0, 0, 0};
    for (int j = beg + lane; j < end; j += 64) {
        int src = bsrc[j];
        float4 A0 = *(const float4*)(asrc + src * 8);
        float4 A1 = *(const float4*)(asrc + src * 8 + 4);
        float sv[8] = {A0.x, A0.y, A0.z, A0.w, A1.x, A1.y, A1.z, A1.w};
#pragma unroll
        for (int h = 0; h < 8; h++) ds[h] += __expf(lrelu(sv[h] + adh[h]) - mx[h]);
    }
#pragma unroll
    for (int h = 0; h < 8; h++) {
#pragma unroll
        for (int o = 32; o; o >>= 1) ds[h] += __shfl_xor(ds[h], o, 64);
    }
    float rd[8];
#pragma unroll
    for (int h = 0; h < 8; h++) rd[h] = 1.f / (ds[h] + 1e-16f);

    // channel-parallel accumulation: lane -> channels 2l, 2l+1, head hh = l>>3
    int hh = lane >> 3;
    float adv = sel8(adh[0], adh[1], adh[2], adh[3], adh[4], adh[5], adh[6], adh[7], hh);
    float mv  = sel8(mx[0], mx[1], mx[2], mx[3], mx[4], mx[5], mx[6], mx[7], hh);
    float rv  = sel8(rd[0], rd[1], rd[2], rd[3], rd[4], rd[5], rd[6], rd[7], hh);

    float acc0 = 0.f, acc1 = 0.f;
    for (int j = beg; j < end; ++j) {
        int src = bsrc[j];
        float sa = asrc[src * 8 + hh];
        float wgt = __expf(lrelu(sa + adv) - mv) * rv;
        f16x2 hv = *(const f16x2*)&h1h[(size_t)src * HH + 2 * lane];
        acc0 += wgt * (float)hv[0];
        acc1 += wgt * (float)hv[1];
    }
    float2 bv = *(const float2*)&b1[2 * lane];
    float v0 = acc0 + bv.x;
    float v1 = acc1 + bv.y;
    v0 = v0 > 0.f ? v0 : __expf(v0) - 1.f;   // ELU
    v1 = v1 > 0.f ? v1 : __expf(v1) - 1.f;
    f16x2 o = {(_Float16)v0, (_Float16)v1};
    *(f16x2*)&h1bh[(size_t)node * HH + 2 * lane] = o;
}

// ---------------- GEMM2: h2h[N,40] = fp16(h1bh[N,128] @ W2[128,40]) ----------------
__global__ __launch_bounds__(256) void gemm2_kernel(const _Float16* __restrict__ h1bh,
                                                    const float* __restrict__ W2,
                                                    _Float16* __restrict__ h2h) {
    __shared__ float Ws[HH * NCLS];
    for (int i = threadIdx.x; i < HH * NCLS; i += 256) Ws[i] = W2[i];
    __syncthreads();
    int idx = blockIdx.x * 256 + threadIdx.x;
    if (idx >= N_NODES * NCLS) return;
    int n = idx / NCLS, c = idx - n * NCLS;
    const f16x8* hp = (const f16x8*)&h1bh[(size_t)n * HH];
    float acc = 0.f;
#pragma unroll
    for (int k8 = 0; k8 < HH / 8; ++k8) {
        f16x8 hv = hp[k8];
#pragma unroll
        for (int i = 0; i < 8; ++i)
            acc += (float)hv[i] * Ws[(k8 * 8 + i) * NCLS + c];
    }
    h2h[idx] = (_Float16)acc;
}

__global__ void alpha2_kernel(const _Float16* __restrict__ h2h,
                              const float* __restrict__ a_src,
                              const float* __restrict__ a_dst,
                              float* __restrict__ asrc, float* __restrict__ adst) {
    int n = blockIdx.x * blockDim.x + threadIdx.x;
    if (n >= N_NODES) return;
    const f16x8* hp = (const f16x8*)&h2h[(size_t)n * NCLS];
    float s = 0.f, d = 0.f;
#pragma unroll
    for (int c8 = 0; c8 < NCLS / 8; ++c8) {
        f16x8 hv = hp[c8];
#pragma unroll
        for (int i = 0; i < 8; ++i) {
            float f = (float)hv[i];
            s += f * a_src[c8 * 8 + i];
            d += f * a_dst[c8 * 8 + i];
        }
    }
    asrc[n] = s;
    adst[n] = d;
}

// ---------------- layer-2 aggregation (1 head, 40 channels) ----------------
__global__ __launch_bounds__(256) void agg2_kernel(const _Float16* __restrict__ h2h,
                                                   const float* __restrict__ asrc,
                                                   const float* __restrict__ adst,
                                                   const int* __restrict__ offs,
                                                   const int* __restrict__ bsrc,
                                                   const float* __restrict__ b2,
                                                   float* __restrict__ out) {
    int lane = threadIdx.x & 63;
    int node = blockIdx.x * 4 + (threadIdx.x >> 6);
    if (node >= N_NODES) return;
    int beg = offs[node], end = offs[node + 1];
    float adv = adst[node];
    float mx = -1e30f;
    for (int j = beg + lane; j < end; j += 64)
        mx = fmaxf(mx, lrelu(asrc[bsrc[j]] + adv));
#pragma unroll
    for (int o = 32; o; o >>= 1) mx = fmaxf(mx, __shfl_xor(mx, o, 64));
    float ds = 0.f;
    for (int j = beg + lane; j < end; j += 64)
        ds += __expf(lrelu(asrc[bsrc[j]] + adv) - mx);
#pragma unroll
    for (int o = 32; o; o >>= 1) ds += __shfl_xor(ds, o, 64);
    float rd = 1.f / (ds + 1e-16f);
    // lane < 20 owns channels 2l, 2l+1
    float acc0 = 0.f, acc1 = 0.f;
    for (int j = beg; j < end; ++j) {
        int src = bsrc[j];
        float w = __expf(lrelu(asrc[src] + adv) - mx) * rd;
        if (lane < NCLS / 2) {
            f16x2 hv = *(const f16x2*)&h2h[(size_t)src * NCLS + 2 * lane];
            acc0 += w * (float)hv[0];
            acc1 += w * (float)hv[1];
        }
    }
    if (lane < NCLS / 2) {
        float2 bv = *(const float2*)&b2[2 * lane];
        float2 ov = make_float2(acc0 + bv.x, acc1 + bv.y);
        *(float2*)&out[(size_t)node * NCLS + 2 * lane] = ov;
    }
}

// ---------------- log_softmax in place on d_out ----------------
__global__ __launch_bounds__(256) void logsoftmax_kernel(float* __restrict__ out) {
    int lane = threadIdx.x & 63;
    int node = blockIdx.x * 4 + (threadIdx.x >> 6);
    if (node >= N_NODES) return;
    float v = (lane < NCLS) ? out[(size_t)node * NCLS + lane] : -1e30f;
    float m = v;
#pragma unroll
    for (int o = 32; o; o >>= 1) m = fmaxf(m, __shfl_xor(m, o, 64));
    float p = (lane < NCLS) ? __expf(v - m) : 0.f;
    float s = p;
#pragma unroll
    for (int o = 32; o; o >>= 1) s += __shfl_xor(s, o, 64);
    float ls = m + __logf(s);
    if (lane < NCLS) out[(size_t)node * NCLS + lane] = v - ls;
}

extern "C" void kernel_launch(void* const* d_in, const int* in_sizes, int n_in,
                              void* d_out, int out_size, void* d_ws, size_t ws_size,
                              hipStream_t stream) {
    const float* x      = (const float*)d_in[0];
    const int*   ei     = (const int*)d_in[1];
    const float* W1     = (const float*)d_in[2];
    const float* a_src1 = (const float*)d_in[3];
    const float* a_dst1 = (const float*)d_in[4];
    const float* b1     = (const float*)d_in[5];
    const float* W2     = (const float*)d_in[6];
    const float* a_src2 = (const float*)d_in[7];
    const float* a_dst2 = (const float*)d_in[8];
    const float* b2     = (const float*)d_in[9];
    float* out = (float*)d_out;

    const int E  = in_sizes[1] / 2;
    const int EP = E + N_NODES;

    char* w = (char*)d_ws;
    _Float16* h1h   = (_Float16*)(w + 0);          // 12,800,000 B
    _Float16* h1bh  = (_Float16*)(w + 12800000);   // 12,800,000 B
    float*    asrc1 = (float*)(w + 25600000);      //  1,600,000 B
    float*    adst1 = (float*)(w + 27200000);      //  1,600,000 B
    _Float16* h2h   = (_Float16*)(w + 28800000);   //  4,000,000 B
    float*    asrc2 = (float*)(w + 32800000);      //    200,000 B
    float*    adst2 = (float*)(w + 33000000);      //    200,000 B
    int*      deg   = (int*)(w + 33200000);        //    200,000 B
    int*      offs  = (int*)(w + 33400064);        //    200,004 B
    int*      cursor= (int*)(w + 33600128);        //    200,000 B
    int*      bsrc  = (int*)(w + 33800192);        //  3,400,000 B
    _Float16* Wt    = (_Float16*)(w + 37200256);   //    131,072 B (end ~37.3 MB)

    zero_int_kernel<<<(N_NODES + 255) / 256, 256, 0, stream>>>(deg, N_NODES);
    convW_kernel<<<(128 * 512 + 255) / 256, 256, 0, stream>>>(W1, Wt);
    gemm1_mfma<<<(N_NODES + 63) / 64, 256, 0, stream>>>(x, Wt, h1h);
    alpha1_kernel<<<(N_NODES * HEADS + 255) / 256, 256, 0, stream>>>(h1h, a_src1, a_dst1,
                                                                     asrc1, adst1);
    count_kernel<<<(EP + 255) / 256, 256, 0, stream>>>(ei, deg, E, EP);
    scan_kernel<<<1, 1024, 0, stream>>>(deg, offs, cursor, N_NODES);
    fill_kernel<<<(EP + 255) / 256, 256, 0, stream>>>(ei, cursor, bsrc, E, EP);
    agg1_kernel<<<(N_NODES + 3) / 4, 256, 0, stream>>>(h1h, asrc1, adst1, offs, bsrc, b1, h1bh);
    gemm2_kernel<<<(N_NODES * NCLS + 255) / 256, 256, 0, stream>>>(h1bh, W2, h2h);
    alpha2_kernel<<<(N_NODES + 255) / 256, 256, 0, stream>>>(h2h, a_src2, a_dst2,
                                                             asrc2, adst2);
    agg2_kernel<<<(N_NODES + 3) / 4, 256, 0, stream>>>(h2h, asrc2, adst2, offs, bsrc, b2, out);
    logsoftmax_kernel<<<(N_NODES + 3) / 4, 256, 0, stream>>>(out);
}

// Round 6
// 547.947 us; speedup vs baseline: 1.5182x; 1.1730x over previous
//
#include <hip/hip_runtime.h>
#include <hip/hip_bf16.h>
#include <math.h>

#define N_NODES 50000
#define F_IN    500
#define HEADS   8
#define HID     16
#define HH      128   // HEADS*HID
#define NCLS    40
#define NEG     0.2f

typedef _Float16 f16x2 __attribute__((ext_vector_type(2)));
typedef _Float16 f16x4 __attribute__((ext_vector_type(4)));
typedef _Float16 f16x8 __attribute__((ext_vector_type(8)));
typedef float    f32x4 __attribute__((ext_vector_type(4)));

__device__ __forceinline__ float lrelu(float x) { return x >= 0.f ? x : NEG * x; }

// -------- convert W1[500][128] -> Wt[128][512] fp16, K zero-padded --------
__global__ void convW_kernel(const float* __restrict__ W1, _Float16* __restrict__ Wt) {
    int i = blockIdx.x * 256 + threadIdx.x;
    if (i >= 128 * 512) return;
    int c = i >> 9, k = i & 511;
    Wt[i] = (k < F_IN) ? (_Float16)W1[k * HH + c] : (_Float16)0.f;
}

// ---------------- GEMM1 (MFMA fp16): h1h[N,128] = fp16(x[N,500] @ W1) ----------------
#define KT   128
#define LDP  136   // padded LDS row stride (halves)
__global__ __launch_bounds__(256) void gemm1_mfma(const float* __restrict__ x,
                                                  const _Float16* __restrict__ Wt,
                                                  _Float16* __restrict__ h1h) {
    __shared__ _Float16 As[64 * LDP];
    __shared__ _Float16 Bs[128 * LDP];
    const int t = threadIdx.x;
    const int lane = t & 63, w = t >> 6;
    const int rowBase = blockIdx.x * 64;

    f32x4 acc[8];
#pragma unroll
    for (int n = 0; n < 8; ++n) acc[n] = (f32x4){0.f, 0.f, 0.f, 0.f};

    const int fa = t & 31, ra = t >> 5;
    const int gb = t & 15, cb = t >> 4;

    for (int kt = 0; kt < 4; ++kt) {
        const int kt0 = kt * KT;
#pragma unroll
        for (int p = 0; p < 8; ++p) {
            int row = ra + 8 * p;
            int grow = rowBase + row;
            int k0 = kt0 + 4 * fa;
            float4 v = make_float4(0.f, 0.f, 0.f, 0.f);
            if (grow < N_NODES && k0 < F_IN)
                v = *(const float4*)&x[(size_t)grow * F_IN + k0];
            f16x4 hv = {(_Float16)v.x, (_Float16)v.y, (_Float16)v.z, (_Float16)v.w};
            *(f16x4*)&As[row * LDP + 4 * fa] = hv;
        }
#pragma unroll
        for (int p = 0; p < 8; ++p) {
            int c = cb + 16 * p;
            *(f16x8*)&Bs[c * LDP + 8 * gb] = *(const f16x8*)&Wt[c * 512 + kt0 + 8 * gb];
        }
        __syncthreads();
#pragma unroll
        for (int ks = 0; ks < 4; ++ks) {
            int kk = ks * 32 + (lane >> 4) * 8;
            f16x8 a = *(const f16x8*)&As[(16 * w + (lane & 15)) * LDP + kk];
#pragma unroll
            for (int n = 0; n < 8; ++n) {
                f16x8 b = *(const f16x8*)&Bs[(16 * n + (lane & 15)) * LDP + kk];
                acc[n] = __builtin_amdgcn_mfma_f32_16x16x32_f16(a, b, acc[n], 0, 0, 0);
            }
        }
        __syncthreads();
    }
    const int colb = lane & 15, rq = lane >> 4;
#pragma unroll
    for (int n = 0; n < 8; ++n) {
#pragma unroll
        for (int r = 0; r < 4; ++r) {
            int grow = rowBase + 16 * w + rq * 4 + r;
            if (grow < N_NODES) h1h[(size_t)grow * HH + 16 * n + colb] = (_Float16)acc[n][r];
        }
    }
}

// ---------------- per-node attention coefficients, layer 1 (fp16 h) ----------------
__global__ void alpha1_kernel(const _Float16* __restrict__ h1h,
                              const float* __restrict__ a_src,
                              const float* __restrict__ a_dst,
                              float* __restrict__ asrc, float* __restrict__ adst) {
    int idx = blockIdx.x * blockDim.x + threadIdx.x;
    if (idx >= N_NODES * HEADS) return;
    int n = idx >> 3, h = idx & 7;
    const f16x8* hp = (const f16x8*)&h1h[(size_t)n * HH + h * HID];
    float s = 0.f, d = 0.f;
#pragma unroll
    for (int c = 0; c < 2; ++c) {
        f16x8 hv = hp[c];
#pragma unroll
        for (int i = 0; i < 8; ++i) {
            float f = (float)hv[i];
            s += f * a_src[h * HID + c * 8 + i];
            d += f * a_dst[h * HID + c * 8 + i];
        }
    }
    asrc[idx] = s;
    adst[idx] = d;
}

// ---------------- CSR build ----------------
__global__ void zero_int_kernel(int* __restrict__ p, int n) {
    int i = blockIdx.x * blockDim.x + threadIdx.x;
    if (i < n) p[i] = 0;
}

__global__ void count_kernel(const int* __restrict__ ei, int* __restrict__ deg,
                             int E, int EP) {
    int e = blockIdx.x * blockDim.x + threadIdx.x;
    if (e >= EP) return;
    int dst = (e < E) ? ei[E + e] : (e - E);
    atomicAdd(&deg[dst], 1);
}

__global__ __launch_bounds__(1024) void scan_kernel(const int* __restrict__ deg,
                                                    int* __restrict__ offs,
                                                    int* __restrict__ cursor, int n) {
    __shared__ int part[1024];
    int tid = threadIdx.x;
    int chunk = (n + 1023) / 1024;
    int start = tid * chunk;
    int end = min(start + chunk, n);
    int s = 0;
    for (int i = start; i < end; i++) s += deg[i];
    part[tid] = s;
    __syncthreads();
    for (int off = 1; off < 1024; off <<= 1) {
        int v = 0;
        if (tid >= off) v = part[tid - off];
        __syncthreads();
        if (tid >= off) part[tid] += v;
        __syncthreads();
    }
    int base = (tid == 0) ? 0 : part[tid - 1];
    for (int i = start; i < end; i++) {
        offs[i] = base;
        cursor[i] = base;
        base += deg[i];
    }
    if (tid == 1023) offs[n] = base;
}

__global__ void fill_kernel(const int* __restrict__ ei, int* __restrict__ cursor,
                            int* __restrict__ bsrc, int E, int EP) {
    int e = blockIdx.x * blockDim.x + threadIdx.x;
    if (e >= EP) return;
    int src, dst;
    if (e < E) { src = ei[e]; dst = ei[E + e]; }
    else       { src = e - E; dst = e - E; }
    int slot = atomicAdd(&cursor[dst], 1);
    bsrc[slot] = src;
}

// ---------------- layer-1 aggregation: one wave per dst node, SINGLE PASS ----------------
// No segment-max (exp(e) directly; |e|<~5 so safe). Lane owns channels 2l,2l+1,
// head hh=l>>3; denom accumulated per-lane. 2x unroll for memory-level parallelism.
__global__ __launch_bounds__(256) void agg1_kernel(const _Float16* __restrict__ h1h,
                                                   const float* __restrict__ asrc,
                                                   const float* __restrict__ adst,
                                                   const int* __restrict__ offs,
                                                   const int* __restrict__ bsrc,
                                                   const float* __restrict__ b1,
                                                   _Float16* __restrict__ h1bh) {
    int lane = threadIdx.x & 63;
    int node = blockIdx.x * 4 + (threadIdx.x >> 6);
    if (node >= N_NODES) return;
    int beg = offs[node], end = offs[node + 1];
    int hh = lane >> 3;
    float adv = adst[node * 8 + hh];

    float acc0 = 0.f, acc1 = 0.f, dsum = 0.f;
    int j = beg;
    for (; j + 2 <= end; j += 2) {
        int s0 = bsrc[j], s1 = bsrc[j + 1];
        float sa0 = asrc[s0 * 8 + hh];
        float sa1 = asrc[s1 * 8 + hh];
        f16x2 hv0 = *(const f16x2*)&h1h[(size_t)s0 * HH + 2 * lane];
        f16x2 hv1 = *(const f16x2*)&h1h[(size_t)s1 * HH + 2 * lane];
        float w0 = __expf(lrelu(sa0 + adv));
        float w1 = __expf(lrelu(sa1 + adv));
        dsum += w0 + w1;
        acc0 += w0 * (float)hv0[0] + w1 * (float)hv1[0];
        acc1 += w0 * (float)hv0[1] + w1 * (float)hv1[1];
    }
    if (j < end) {
        int s0 = bsrc[j];
        float sa0 = asrc[s0 * 8 + hh];
        f16x2 hv0 = *(const f16x2*)&h1h[(size_t)s0 * HH + 2 * lane];
        float w0 = __expf(lrelu(sa0 + adv));
        dsum += w0;
        acc0 += w0 * (float)hv0[0];
        acc1 += w0 * (float)hv0[1];
    }
    float rv = 1.f / (dsum + 1e-16f);
    float2 bv = *(const float2*)&b1[2 * lane];
    float v0 = acc0 * rv + bv.x;
    float v1 = acc1 * rv + bv.y;
    v0 = v0 > 0.f ? v0 : __expf(v0) - 1.f;   // ELU
    v1 = v1 > 0.f ? v1 : __expf(v1) - 1.f;
    f16x2 o = {(_Float16)v0, (_Float16)v1};
    *(f16x2*)&h1bh[(size_t)node * HH + 2 * lane] = o;
}

// ---------------- GEMM2: h2h[N,40] = fp16(h1bh[N,128] @ W2[128,40]) ----------------
__global__ __launch_bounds__(256) void gemm2_kernel(const _Float16* __restrict__ h1bh,
                                                    const float* __restrict__ W2,
                                                    _Float16* __restrict__ h2h) {
    __shared__ float Ws[HH * NCLS];
    for (int i = threadIdx.x; i < HH * NCLS; i += 256) Ws[i] = W2[i];
    __syncthreads();
    int idx = blockIdx.x * 256 + threadIdx.x;
    if (idx >= N_NODES * NCLS) return;
    int n = idx / NCLS, c = idx - n * NCLS;
    const f16x8* hp = (const f16x8*)&h1bh[(size_t)n * HH];
    float acc = 0.f;
#pragma unroll
    for (int k8 = 0; k8 < HH / 8; ++k8) {
        f16x8 hv = hp[k8];
#pragma unroll
        for (int i = 0; i < 8; ++i)
            acc += (float)hv[i] * Ws[(k8 * 8 + i) * NCLS + c];
    }
    h2h[idx] = (_Float16)acc;
}

__global__ void alpha2_kernel(const _Float16* __restrict__ h2h,
                              const float* __restrict__ a_src,
                              const float* __restrict__ a_dst,
                              float* __restrict__ asrc, float* __restrict__ adst) {
    int n = blockIdx.x * blockDim.x + threadIdx.x;
    if (n >= N_NODES) return;
    const f16x8* hp = (const f16x8*)&h2h[(size_t)n * NCLS];
    float s = 0.f, d = 0.f;
#pragma unroll
    for (int c8 = 0; c8 < NCLS / 8; ++c8) {
        f16x8 hv = hp[c8];
#pragma unroll
        for (int i = 0; i < 8; ++i) {
            float f = (float)hv[i];
            s += f * a_src[c8 * 8 + i];
            d += f * a_dst[c8 * 8 + i];
        }
    }
    asrc[n] = s;
    adst[n] = d;
}

// ------- layer-2 aggregation, SINGLE PASS, fused log_softmax (1 head, 40 ch) -------
__global__ __launch_bounds__(256) void agg2_kernel(const _Float16* __restrict__ h2h,
                                                   const float* __restrict__ asrc,
                                                   const float* __restrict__ adst,
                                                   const int* __restrict__ offs,
                                                   const int* __restrict__ bsrc,
                                                   const float* __restrict__ b2,
                                                   float* __restrict__ out) {
    int lane = threadIdx.x & 63;
    int node = blockIdx.x * 4 + (threadIdx.x >> 6);
    if (node >= N_NODES) return;
    int beg = offs[node], end = offs[node + 1];
    float adv = adst[node];
    bool act = lane < NCLS / 2;

    float acc0 = 0.f, acc1 = 0.f, dsum = 0.f;
    int j = beg;
    for (; j + 2 <= end; j += 2) {
        int s0 = bsrc[j], s1 = bsrc[j + 1];
        float w0 = __expf(lrelu(asrc[s0] + adv));
        float w1 = __expf(lrelu(asrc[s1] + adv));
        f16x2 hv0 = {(_Float16)0.f, (_Float16)0.f}, hv1 = hv0;
        if (act) {
            hv0 = *(const f16x2*)&h2h[(size_t)s0 * NCLS + 2 * lane];
            hv1 = *(const f16x2*)&h2h[(size_t)s1 * NCLS + 2 * lane];
        }
        dsum += w0 + w1;
        acc0 += w0 * (float)hv0[0] + w1 * (float)hv1[0];
        acc1 += w0 * (float)hv0[1] + w1 * (float)hv1[1];
    }
    if (j < end) {
        int s0 = bsrc[j];
        float w0 = __expf(lrelu(asrc[s0] + adv));
        f16x2 hv0 = {(_Float16)0.f, (_Float16)0.f};
        if (act) hv0 = *(const f16x2*)&h2h[(size_t)s0 * NCLS + 2 * lane];
        dsum += w0;
        acc0 += w0 * (float)hv0[0];
        acc1 += w0 * (float)hv0[1];
    }
    float rd = 1.f / (dsum + 1e-16f);
    float v0 = -1e30f, v1 = -1e30f;
    if (act) {
        float2 bv = *(const float2*)&b2[2 * lane];
        v0 = acc0 * rd + bv.x;
        v1 = acc1 * rd + bv.y;
    }
    // fused log_softmax over the 40 channels held in lanes 0..19
    float m = fmaxf(v0, v1);
#pragma unroll
    for (int o = 32; o; o >>= 1) m = fmaxf(m, __shfl_xor(m, o, 64));
    float p = act ? (__expf(v0 - m) + __expf(v1 - m)) : 0.f;
#pragma unroll
    for (int o = 32; o; o >>= 1) p += __shfl_xor(p, o, 64);
    float ls = m + __logf(p);
    if (act) {
        float2 ov = make_float2(v0 - ls, v1 - ls);
        *(float2*)&out[(size_t)node * NCLS + 2 * lane] = ov;
    }
}

extern "C" void kernel_launch(void* const* d_in, const int* in_sizes, int n_in,
                              void* d_out, int out_size, void* d_ws, size_t ws_size,
                              hipStream_t stream) {
    const float* x      = (const float*)d_in[0];
    const int*   ei     = (const int*)d_in[1];
    const float* W1     = (const float*)d_in[2];
    const float* a_src1 = (const float*)d_in[3];
    const float* a_dst1 = (const float*)d_in[4];
    const float* b1     = (const float*)d_in[5];
    const float* W2     = (const float*)d_in[6];
    const float* a_src2 = (const float*)d_in[7];
    const float* a_dst2 = (const float*)d_in[8];
    const float* b2     = (const float*)d_in[9];
    float* out = (float*)d_out;

    const int E  = in_sizes[1] / 2;
    const int EP = E + N_NODES;

    char* w = (char*)d_ws;
    _Float16* h1h   = (_Float16*)(w + 0);          // 12,800,000 B
    _Float16* h1bh  = (_Float16*)(w + 12800000);   // 12,800,000 B
    float*    asrc1 = (float*)(w + 25600000);      //  1,600,000 B
    float*    adst1 = (float*)(w + 27200000);      //  1,600,000 B
    _Float16* h2h   = (_Float16*)(w + 28800000);   //  4,000,000 B
    float*    asrc2 = (float*)(w + 32800000);      //    200,000 B
    float*    adst2 = (float*)(w + 33000000);      //    200,000 B
    int*      deg   = (int*)(w + 33200000);        //    200,000 B
    int*      offs  = (int*)(w + 33400064);        //    200,004 B
    int*      cursor= (int*)(w + 33600128);        //    200,000 B
    int*      bsrc  = (int*)(w + 33800192);        //  3,400,000 B
    _Float16* Wt    = (_Float16*)(w + 37200256);   //    131,072 B (end ~37.3 MB)

    zero_int_kernel<<<(N_NODES + 255) / 256, 256, 0, stream>>>(deg, N_NODES);
    convW_kernel<<<(128 * 512 + 255) / 256, 256, 0, stream>>>(W1, Wt);
    gemm1_mfma<<<(N_NODES + 63) / 64, 256, 0, stream>>>(x, Wt, h1h);
    alpha1_kernel<<<(N_NODES * HEADS + 255) / 256, 256, 0, stream>>>(h1h, a_src1, a_dst1,
                                                                     asrc1, adst1);
    count_kernel<<<(EP + 255) / 256, 256, 0, stream>>>(ei, deg, E, EP);
    scan_kernel<<<1, 1024, 0, stream>>>(deg, offs, cursor, N_NODES);
    fill_kernel<<<(EP + 255) / 256, 256, 0, stream>>>(ei, cursor, bsrc, E, EP);
    agg1_kernel<<<(N_NODES + 3) / 4, 256, 0, stream>>>(h1h, asrc1, adst1, offs, bsrc, b1, h1bh);
    gemm2_kernel<<<(N_NODES * NCLS + 255) / 256, 256, 0, stream>>>(h1bh, W2, h2h);
    alpha2_kernel<<<(N_NODES + 255) / 256, 256, 0, stream>>>(h2h, a_src2, a_dst2,
                                                             asrc2, adst2);
    agg2_kernel<<<(N_NODES + 3) / 4, 256, 0, stream>>>(h2h, asrc2, adst2, offs, bsrc, b2, out);
}

// Round 7
// 446.693 us; speedup vs baseline: 1.8623x; 1.2267x over previous
//
#include <hip/hip_runtime.h>
#include <hip/hip_bf16.h>
#include <math.h>

#define N_NODES 50000
#define F_IN    500
#define HEADS   8
#define HID     16
#define HH      128   // HEADS*HID
#define NCLS    40
#define NEG     0.2f

typedef _Float16 f16x2 __attribute__((ext_vector_type(2)));
typedef _Float16 f16x4 __attribute__((ext_vector_type(4)));
typedef _Float16 f16x8 __attribute__((ext_vector_type(8)));
typedef float    f32x4 __attribute__((ext_vector_type(4)));

__device__ __forceinline__ float lrelu(float x) { return x >= 0.f ? x : NEG * x; }

// -------- convert W1[500][128] -> Wt[128][512] fp16, K zero-padded --------
__global__ void convW_kernel(const float* __restrict__ W1, _Float16* __restrict__ Wt) {
    int i = blockIdx.x * 256 + threadIdx.x;
    if (i >= 128 * 512) return;
    int c = i >> 9, k = i & 511;
    Wt[i] = (k < F_IN) ? (_Float16)W1[k * HH + c] : (_Float16)0.f;
}

// ---------------- GEMM1 (MFMA fp16): h1h[N,128] = fp16(x[N,500] @ W1) ----------------
#define KT   128
#define LDP  136   // padded LDS row stride (halves)
__global__ __launch_bounds__(256) void gemm1_mfma(const float* __restrict__ x,
                                                  const _Float16* __restrict__ Wt,
                                                  _Float16* __restrict__ h1h) {
    __shared__ _Float16 As[64 * LDP];
    __shared__ _Float16 Bs[128 * LDP];
    const int t = threadIdx.x;
    const int lane = t & 63, w = t >> 6;
    const int rowBase = blockIdx.x * 64;

    f32x4 acc[8];
#pragma unroll
    for (int n = 0; n < 8; ++n) acc[n] = (f32x4){0.f, 0.f, 0.f, 0.f};

    const int fa = t & 31, ra = t >> 5;
    const int gb = t & 15, cb = t >> 4;

    for (int kt = 0; kt < 4; ++kt) {
        const int kt0 = kt * KT;
#pragma unroll
        for (int p = 0; p < 8; ++p) {
            int row = ra + 8 * p;
            int grow = rowBase + row;
            int k0 = kt0 + 4 * fa;
            float4 v = make_float4(0.f, 0.f, 0.f, 0.f);
            if (grow < N_NODES && k0 < F_IN)
                v = *(const float4*)&x[(size_t)grow * F_IN + k0];
            f16x4 hv = {(_Float16)v.x, (_Float16)v.y, (_Float16)v.z, (_Float16)v.w};
            *(f16x4*)&As[row * LDP + 4 * fa] = hv;
        }
#pragma unroll
        for (int p = 0; p < 8; ++p) {
            int c = cb + 16 * p;
            *(f16x8*)&Bs[c * LDP + 8 * gb] = *(const f16x8*)&Wt[c * 512 + kt0 + 8 * gb];
        }
        __syncthreads();
#pragma unroll
        for (int ks = 0; ks < 4; ++ks) {
            int kk = ks * 32 + (lane >> 4) * 8;
            f16x8 a = *(const f16x8*)&As[(16 * w + (lane & 15)) * LDP + kk];
#pragma unroll
            for (int n = 0; n < 8; ++n) {
                f16x8 b = *(const f16x8*)&Bs[(16 * n + (lane & 15)) * LDP + kk];
                acc[n] = __builtin_amdgcn_mfma_f32_16x16x32_f16(a, b, acc[n], 0, 0, 0);
            }
        }
        __syncthreads();
    }
    const int colb = lane & 15, rq = lane >> 4;
#pragma unroll
    for (int n = 0; n < 8; ++n) {
#pragma unroll
        for (int r = 0; r < 4; ++r) {
            int grow = rowBase + 16 * w + rq * 4 + r;
            if (grow < N_NODES) h1h[(size_t)grow * HH + 16 * n + colb] = (_Float16)acc[n][r];
        }
    }
}

// ---------------- per-node attention coefficients, layer 1 (fp16 h) ----------------
__global__ void alpha1_kernel(const _Float16* __restrict__ h1h,
                              const float* __restrict__ a_src,
                              const float* __restrict__ a_dst,
                              float* __restrict__ asrc, float* __restrict__ adst) {
    int idx = blockIdx.x * blockDim.x + threadIdx.x;
    if (idx >= N_NODES * HEADS) return;
    int n = idx >> 3, h = idx & 7;
    const f16x8* hp = (const f16x8*)&h1h[(size_t)n * HH + h * HID];
    float s = 0.f, d = 0.f;
#pragma unroll
    for (int c = 0; c < 2; ++c) {
        f16x8 hv = hp[c];
#pragma unroll
        for (int i = 0; i < 8; ++i) {
            float f = (float)hv[i];
            s += f * a_src[h * HID + c * 8 + i];
            d += f * a_dst[h * HID + c * 8 + i];
        }
    }
    asrc[idx] = s;
    adst[idx] = d;
}

// ---------------- CSR build ----------------
__global__ void zero_int_kernel(int* __restrict__ p, int n) {
    int i = blockIdx.x * blockDim.x + threadIdx.x;
    if (i < n) p[i] = 0;
}

__global__ void count_kernel(const int* __restrict__ ei, int* __restrict__ deg,
                             int E, int EP) {
    int e = blockIdx.x * blockDim.x + threadIdx.x;
    if (e >= EP) return;
    int dst = (e < E) ? ei[E + e] : (e - E);
    atomicAdd(&deg[dst], 1);
}

// ---- two-level parallel scan: scan1 (in-block) -> scan2 (block sums) -> scan3 (apply) ----
__global__ __launch_bounds__(256) void scan1_kernel(const int* __restrict__ deg,
                                                    int* __restrict__ offs,
                                                    int* __restrict__ bsums, int n) {
    __shared__ int sm[256];
    int tid = threadIdx.x, i = blockIdx.x * 256 + tid;
    int v = (i < n) ? deg[i] : 0;
    sm[tid] = v;
    __syncthreads();
    for (int off = 1; off < 256; off <<= 1) {
        int t = 0;
        if (tid >= off) t = sm[tid - off];
        __syncthreads();
        if (tid >= off) sm[tid] += t;
        __syncthreads();
    }
    if (i < n) offs[i] = sm[tid] - v;            // exclusive within block
    if (tid == 255) bsums[blockIdx.x] = sm[255]; // block total
}

__global__ __launch_bounds__(256) void scan2_kernel(const int* __restrict__ bsums,
                                                    int* __restrict__ boffs, int nb,
                                                    int* __restrict__ offs, int n) {
    __shared__ int sm[256];
    int tid = threadIdx.x;
    int v = (tid < nb) ? bsums[tid] : 0;
    sm[tid] = v;
    __syncthreads();
    for (int off = 1; off < 256; off <<= 1) {
        int t = 0;
        if (tid >= off) t = sm[tid - off];
        __syncthreads();
        if (tid >= off) sm[tid] += t;
        __syncthreads();
    }
    if (tid < nb) boffs[tid] = sm[tid] - v;      // exclusive block offsets
    if (tid == 255) offs[n] = sm[255];           // grand total
}

__global__ __launch_bounds__(256) void scan3_kernel(int* __restrict__ offs,
                                                    int* __restrict__ cursor,
                                                    const int* __restrict__ boffs, int n) {
    int i = blockIdx.x * 256 + threadIdx.x;
    if (i >= n) return;
    int o = offs[i] + boffs[blockIdx.x];
    offs[i] = o;
    cursor[i] = o;
}

__global__ void fill_kernel(const int* __restrict__ ei, int* __restrict__ cursor,
                            int* __restrict__ bsrc, int E, int EP) {
    int e = blockIdx.x * blockDim.x + threadIdx.x;
    if (e >= EP) return;
    int src, dst;
    if (e < E) { src = ei[e]; dst = ei[E + e]; }
    else       { src = e - E; dst = e - E; }
    int slot = atomicAdd(&cursor[dst], 1);
    bsrc[slot] = src;
}

// ---------------- layer-1 aggregation: one wave per dst node, SINGLE PASS ----------------
__global__ __launch_bounds__(256) void agg1_kernel(const _Float16* __restrict__ h1h,
                                                   const float* __restrict__ asrc,
                                                   const float* __restrict__ adst,
                                                   const int* __restrict__ offs,
                                                   const int* __restrict__ bsrc,
                                                   const float* __restrict__ b1,
                                                   _Float16* __restrict__ h1bh) {
    int lane = threadIdx.x & 63;
    int node = blockIdx.x * 4 + (threadIdx.x >> 6);
    if (node >= N_NODES) return;
    int beg = offs[node], end = offs[node + 1];
    int hh = lane >> 3;
    float adv = adst[node * 8 + hh];

    float acc0 = 0.f, acc1 = 0.f, dsum = 0.f;
    int j = beg;
    for (; j + 2 <= end; j += 2) {
        int s0 = bsrc[j], s1 = bsrc[j + 1];
        float sa0 = asrc[s0 * 8 + hh];
        float sa1 = asrc[s1 * 8 + hh];
        f16x2 hv0 = *(const f16x2*)&h1h[(size_t)s0 * HH + 2 * lane];
        f16x2 hv1 = *(const f16x2*)&h1h[(size_t)s1 * HH + 2 * lane];
        float w0 = __expf(lrelu(sa0 + adv));
        float w1 = __expf(lrelu(sa1 + adv));
        dsum += w0 + w1;
        acc0 += w0 * (float)hv0[0] + w1 * (float)hv1[0];
        acc1 += w0 * (float)hv0[1] + w1 * (float)hv1[1];
    }
    if (j < end) {
        int s0 = bsrc[j];
        float sa0 = asrc[s0 * 8 + hh];
        f16x2 hv0 = *(const f16x2*)&h1h[(size_t)s0 * HH + 2 * lane];
        float w0 = __expf(lrelu(sa0 + adv));
        dsum += w0;
        acc0 += w0 * (float)hv0[0];
        acc1 += w0 * (float)hv0[1];
    }
    float rv = 1.f / (dsum + 1e-16f);
    float2 bv = *(const float2*)&b1[2 * lane];
    float v0 = acc0 * rv + bv.x;
    float v1 = acc1 * rv + bv.y;
    v0 = v0 > 0.f ? v0 : __expf(v0) - 1.f;   // ELU
    v1 = v1 > 0.f ? v1 : __expf(v1) - 1.f;
    f16x2 o = {(_Float16)v0, (_Float16)v1};
    *(f16x2*)&h1bh[(size_t)node * HH + 2 * lane] = o;
}

// ---------------- GEMM2: h2h[N,40] = fp16(h1bh[N,128] @ W2[128,40]) ----------------
__global__ __launch_bounds__(256) void gemm2_kernel(const _Float16* __restrict__ h1bh,
                                                    const float* __restrict__ W2,
                                                    _Float16* __restrict__ h2h) {
    __shared__ float Ws[HH * NCLS];
    for (int i = threadIdx.x; i < HH * NCLS; i += 256) Ws[i] = W2[i];
    __syncthreads();
    int idx = blockIdx.x * 256 + threadIdx.x;
    if (idx >= N_NODES * NCLS) return;
    int n = idx / NCLS, c = idx - n * NCLS;
    const f16x8* hp = (const f16x8*)&h1bh[(size_t)n * HH];
    float acc = 0.f;
#pragma unroll
    for (int k8 = 0; k8 < HH / 8; ++k8) {
        f16x8 hv = hp[k8];
#pragma unroll
        for (int i = 0; i < 8; ++i)
            acc += (float)hv[i] * Ws[(k8 * 8 + i) * NCLS + c];
    }
    h2h[idx] = (_Float16)acc;
}

__global__ void alpha2_kernel(const _Float16* __restrict__ h2h,
                              const float* __restrict__ a_src,
                              const float* __restrict__ a_dst,
                              float* __restrict__ asrc, float* __restrict__ adst) {
    int n = blockIdx.x * blockDim.x + threadIdx.x;
    if (n >= N_NODES) return;
    const f16x8* hp = (const f16x8*)&h2h[(size_t)n * NCLS];
    float s = 0.f, d = 0.f;
#pragma unroll
    for (int c8 = 0; c8 < NCLS / 8; ++c8) {
        f16x8 hv = hp[c8];
#pragma unroll
        for (int i = 0; i < 8; ++i) {
            float f = (float)hv[i];
            s += f * a_src[c8 * 8 + i];
            d += f * a_dst[c8 * 8 + i];
        }
    }
    asrc[n] = s;
    adst[n] = d;
}

// ------- layer-2 aggregation, SINGLE PASS, fused log_softmax (1 head, 40 ch) -------
__global__ __launch_bounds__(256) void agg2_kernel(const _Float16* __restrict__ h2h,
                                                   const float* __restrict__ asrc,
                                                   const float* __restrict__ adst,
                                                   const int* __restrict__ offs,
                                                   const int* __restrict__ bsrc,
                                                   const float* __restrict__ b2,
                                                   float* __restrict__ out) {
    int lane = threadIdx.x & 63;
    int node = blockIdx.x * 4 + (threadIdx.x >> 6);
    if (node >= N_NODES) return;
    int beg = offs[node], end = offs[node + 1];
    float adv = adst[node];
    bool act = lane < NCLS / 2;

    float acc0 = 0.f, acc1 = 0.f, dsum = 0.f;
    int j = beg;
    for (; j + 2 <= end; j += 2) {
        int s0 = bsrc[j], s1 = bsrc[j + 1];
        float w0 = __expf(lrelu(asrc[s0] + adv));
        float w1 = __expf(lrelu(asrc[s1] + adv));
        f16x2 hv0 = {(_Float16)0.f, (_Float16)0.f}, hv1 = hv0;
        if (act) {
            hv0 = *(const f16x2*)&h2h[(size_t)s0 * NCLS + 2 * lane];
            hv1 = *(const f16x2*)&h2h[(size_t)s1 * NCLS + 2 * lane];
        }
        dsum += w0 + w1;
        acc0 += w0 * (float)hv0[0] + w1 * (float)hv1[0];
        acc1 += w0 * (float)hv0[1] + w1 * (float)hv1[1];
    }
    if (j < end) {
        int s0 = bsrc[j];
        float w0 = __expf(lrelu(asrc[s0] + adv));
        f16x2 hv0 = {(_Float16)0.f, (_Float16)0.f};
        if (act) hv0 = *(const f16x2*)&h2h[(size_t)s0 * NCLS + 2 * lane];
        dsum += w0;
        acc0 += w0 * (float)hv0[0];
        acc1 += w0 * (float)hv0[1];
    }
    float rd = 1.f / (dsum + 1e-16f);
    float v0 = -1e30f, v1 = -1e30f;
    if (act) {
        float2 bv = *(const float2*)&b2[2 * lane];
        v0 = acc0 * rd + bv.x;
        v1 = acc1 * rd + bv.y;
    }
    float m = fmaxf(v0, v1);
#pragma unroll
    for (int o = 32; o; o >>= 1) m = fmaxf(m, __shfl_xor(m, o, 64));
    float p = act ? (__expf(v0 - m) + __expf(v1 - m)) : 0.f;
#pragma unroll
    for (int o = 32; o; o >>= 1) p += __shfl_xor(p, o, 64);
    float ls = m + __logf(p);
    if (act) {
        float2 ov = make_float2(v0 - ls, v1 - ls);
        *(float2*)&out[(size_t)node * NCLS + 2 * lane] = ov;
    }
}

extern "C" void kernel_launch(void* const* d_in, const int* in_sizes, int n_in,
                              void* d_out, int out_size, void* d_ws, size_t ws_size,
                              hipStream_t stream) {
    const float* x      = (const float*)d_in[0];
    const int*   ei     = (const int*)d_in[1];
    const float* W1     = (const float*)d_in[2];
    const float* a_src1 = (const float*)d_in[3];
    const float* a_dst1 = (const float*)d_in[4];
    const float* b1     = (const float*)d_in[5];
    const float* W2     = (const float*)d_in[6];
    const float* a_src2 = (const float*)d_in[7];
    const float* a_dst2 = (const float*)d_in[8];
    const float* b2     = (const float*)d_in[9];
    float* out = (float*)d_out;

    const int E  = in_sizes[1] / 2;
    const int EP = E + N_NODES;
    const int NB = (N_NODES + 255) / 256;   // 196 scan blocks

    char* w = (char*)d_ws;
    _Float16* h1h   = (_Float16*)(w + 0);          // 12,800,000 B
    _Float16* h1bh  = (_Float16*)(w + 12800000);   // 12,800,000 B
    float*    asrc1 = (float*)(w + 25600000);      //  1,600,000 B
    float*    adst1 = (float*)(w + 27200000);      //  1,600,000 B
    _Float16* h2h   = (_Float16*)(w + 28800000);   //  4,000,000 B
    float*    asrc2 = (float*)(w + 32800000);      //    200,000 B
    float*    adst2 = (float*)(w + 33000000);      //    200,000 B
    int*      deg   = (int*)(w + 33200000);        //    200,000 B
    int*      offs  = (int*)(w + 33400064);        //    200,004 B
    int*      cursor= (int*)(w + 33600128);        //    200,000 B
    int*      bsrc  = (int*)(w + 33800192);        //  3,400,000 B
    _Float16* Wt    = (_Float16*)(w + 37200256);   //    131,072 B
    int*      bsums = (int*)(w + 37331328);        //      1,024 B
    int*      boffs = (int*)(w + 37332352);        //      1,024 B (end ~37.3 MB)

    zero_int_kernel<<<(N_NODES + 255) / 256, 256, 0, stream>>>(deg, N_NODES);
    convW_kernel<<<(128 * 512 + 255) / 256, 256, 0, stream>>>(W1, Wt);
    gemm1_mfma<<<(N_NODES + 63) / 64, 256, 0, stream>>>(x, Wt, h1h);
    alpha1_kernel<<<(N_NODES * HEADS + 255) / 256, 256, 0, stream>>>(h1h, a_src1, a_dst1,
                                                                     asrc1, adst1);
    count_kernel<<<(EP + 255) / 256, 256, 0, stream>>>(ei, deg, E, EP);
    scan1_kernel<<<NB, 256, 0, stream>>>(deg, offs, bsums, N_NODES);
    scan2_kernel<<<1, 256, 0, stream>>>(bsums, boffs, NB, offs, N_NODES);
    scan3_kernel<<<NB, 256, 0, stream>>>(offs, cursor, boffs, N_NODES);
    fill_kernel<<<(EP + 255) / 256, 256, 0, stream>>>(ei, cursor, bsrc, E, EP);
    agg1_kernel<<<(N_NODES + 3) / 4, 256, 0, stream>>>(h1h, asrc1, adst1, offs, bsrc, b1, h1bh);
    gemm2_kernel<<<(N_NODES * NCLS + 255) / 256, 256, 0, stream>>>(h1bh, W2, h2h);
    alpha2_kernel<<<(N_NODES + 255) / 256, 256, 0, stream>>>(h2h, a_src2, a_dst2,
                                                             asrc2, adst2);
    agg2_kernel<<<(N_NODES + 3) / 4, 256, 0, stream>>>(h2h, asrc2, adst2, offs, bsrc, b2, out);
}

// Round 8
// 442.511 us; speedup vs baseline: 1.8799x; 1.0095x over previous
//
#include <hip/hip_runtime.h>
#include <hip/hip_bf16.h>
#include <math.h>

#define N_NODES 50000
#define F_IN    500
#define HEADS   8
#define HID     16
#define HH      128   // HEADS*HID
#define NCLS    40
#define NEG     0.2f

typedef _Float16 f16x2 __attribute__((ext_vector_type(2)));
typedef _Float16 f16x4 __attribute__((ext_vector_type(4)));
typedef _Float16 f16x8 __attribute__((ext_vector_type(8)));
typedef float    f32x4 __attribute__((ext_vector_type(4)));

__device__ __forceinline__ float lrelu(float x) { return x >= 0.f ? x : NEG * x; }

// -------- convert W1[500][128] -> Wt[128][512] fp16, K zero-padded --------
__global__ void convW_kernel(const float* __restrict__ W1, _Float16* __restrict__ Wt) {
    int i = blockIdx.x * 256 + threadIdx.x;
    if (i >= 128 * 512) return;
    int c = i >> 9, k = i & 511;
    Wt[i] = (k < F_IN) ? (_Float16)W1[k * HH + c] : (_Float16)0.f;
}

// ---------------- GEMM1 (MFMA fp16): h1h[N,128] = fp16(x[N,500] @ W1) ----------------
// A-path: NO LDS — each lane builds its MFMA A-fragment directly from global x
// (row = 16w+(lane&15), k = ks*32+(lane>>4)*8), with one-K-tile-ahead register
// prefetch. B staged in LDS per K-tile (L2-resident Wt), padded rows (2-way only).
#define LDPB 136   // padded B row stride (halves)
__global__ __launch_bounds__(256) void gemm1_mfma(const float* __restrict__ x,
                                                  const _Float16* __restrict__ Wt,
                                                  _Float16* __restrict__ h1h) {
    __shared__ _Float16 Bs[128 * LDPB];
    const int t = threadIdx.x;
    const int lane = t & 63, w = t >> 6;
    const int rowBase = blockIdx.x * 64;
    const int arow = rowBase + 16 * w + (lane & 15);
    const bool rowok = arow < N_NODES;
    const int klo = (lane >> 4) * 8;          // 0,8,16,24
    const float* xrow = x + (size_t)arow * F_IN;

    f32x4 acc[8];
#pragma unroll
    for (int n = 0; n < 8; ++n) acc[n] = (f32x4){0.f, 0.f, 0.f, 0.f};

    const int gb = t & 15, cb = t >> 4;       // B staging indices

    float4 pa0[4], pa1[4];                    // prefetched A (2 float4 per ks)
#pragma unroll
    for (int ks = 0; ks < 4; ++ks) {
        int kk = ks * 32 + klo;
        pa0[ks] = (rowok && kk < F_IN)     ? *(const float4*)&xrow[kk]     : make_float4(0, 0, 0, 0);
        pa1[ks] = (rowok && kk + 4 < F_IN) ? *(const float4*)&xrow[kk + 4] : make_float4(0, 0, 0, 0);
    }

    for (int kt = 0; kt < 4; ++kt) {
        // stage B tile kt (from L2-resident Wt)
#pragma unroll
        for (int p = 0; p < 8; ++p) {
            int c = cb + 16 * p;
            *(f16x8*)&Bs[c * LDPB + 8 * gb] = *(const f16x8*)&Wt[c * 512 + kt * 128 + 8 * gb];
        }
        __syncthreads();

        // convert prefetched A to fragments
        f16x8 afr[4];
#pragma unroll
        for (int ks = 0; ks < 4; ++ks) {
            float4 a0 = pa0[ks], a1 = pa1[ks];
            afr[ks] = (f16x8){(_Float16)a0.x, (_Float16)a0.y, (_Float16)a0.z, (_Float16)a0.w,
                              (_Float16)a1.x, (_Float16)a1.y, (_Float16)a1.z, (_Float16)a1.w};
        }
        // prefetch next K-tile's A while MFMAs run
        if (kt < 3) {
#pragma unroll
            for (int ks = 0; ks < 4; ++ks) {
                int kk = (kt + 1) * 128 + ks * 32 + klo;
                pa0[ks] = (rowok && kk < F_IN)     ? *(const float4*)&xrow[kk]     : make_float4(0, 0, 0, 0);
                pa1[ks] = (rowok && kk + 4 < F_IN) ? *(const float4*)&xrow[kk + 4] : make_float4(0, 0, 0, 0);
            }
        }
#pragma unroll
        for (int ks = 0; ks < 4; ++ks) {
#pragma unroll
            for (int n = 0; n < 8; ++n) {
                f16x8 b = *(const f16x8*)&Bs[(16 * n + (lane & 15)) * LDPB + ks * 32 + klo];
                acc[n] = __builtin_amdgcn_mfma_f32_16x16x32_f16(afr[ks], b, acc[n], 0, 0, 0);
            }
        }
        __syncthreads();
    }
    // epilogue: D layout col=lane&15, row=(lane>>4)*4+reg
    const int colb = lane & 15, rq = lane >> 4;
#pragma unroll
    for (int n = 0; n < 8; ++n) {
#pragma unroll
        for (int r = 0; r < 4; ++r) {
            int grow = rowBase + 16 * w + rq * 4 + r;
            if (grow < N_NODES) h1h[(size_t)grow * HH + 16 * n + colb] = (_Float16)acc[n][r];
        }
    }
}

// ---------------- per-node attention coefficients, layer 1 (fp16 h) ----------------
__global__ void alpha1_kernel(const _Float16* __restrict__ h1h,
                              const float* __restrict__ a_src,
                              const float* __restrict__ a_dst,
                              float* __restrict__ asrc, float* __restrict__ adst) {
    int idx = blockIdx.x * blockDim.x + threadIdx.x;
    if (idx >= N_NODES * HEADS) return;
    int n = idx >> 3, h = idx & 7;
    const f16x8* hp = (const f16x8*)&h1h[(size_t)n * HH + h * HID];
    float s = 0.f, d = 0.f;
#pragma unroll
    for (int c = 0; c < 2; ++c) {
        f16x8 hv = hp[c];
#pragma unroll
        for (int i = 0; i < 8; ++i) {
            float f = (float)hv[i];
            s += f * a_src[h * HID + c * 8 + i];
            d += f * a_dst[h * HID + c * 8 + i];
        }
    }
    asrc[idx] = s;
    adst[idx] = d;
}

// ---------------- CSR build ----------------
__global__ void zero_int_kernel(int* __restrict__ p, int n) {
    int i = blockIdx.x * blockDim.x + threadIdx.x;
    if (i < n) p[i] = 0;
}

__global__ void count_kernel(const int* __restrict__ ei, int* __restrict__ deg,
                             int E, int EP) {
    int e = blockIdx.x * blockDim.x + threadIdx.x;
    if (e >= EP) return;
    int dst = (e < E) ? ei[E + e] : (e - E);
    atomicAdd(&deg[dst], 1);
}

// ---- two-level parallel scan ----
__global__ __launch_bounds__(256) void scan1_kernel(const int* __restrict__ deg,
                                                    int* __restrict__ offs,
                                                    int* __restrict__ bsums, int n) {
    __shared__ int sm[256];
    int tid = threadIdx.x, i = blockIdx.x * 256 + tid;
    int v = (i < n) ? deg[i] : 0;
    sm[tid] = v;
    __syncthreads();
    for (int off = 1; off < 256; off <<= 1) {
        int t = 0;
        if (tid >= off) t = sm[tid - off];
        __syncthreads();
        if (tid >= off) sm[tid] += t;
        __syncthreads();
    }
    if (i < n) offs[i] = sm[tid] - v;
    if (tid == 255) bsums[blockIdx.x] = sm[255];
}

__global__ __launch_bounds__(256) void scan2_kernel(const int* __restrict__ bsums,
                                                    int* __restrict__ boffs, int nb,
                                                    int* __restrict__ offs, int n) {
    __shared__ int sm[256];
    int tid = threadIdx.x;
    int v = (tid < nb) ? bsums[tid] : 0;
    sm[tid] = v;
    __syncthreads();
    for (int off = 1; off < 256; off <<= 1) {
        int t = 0;
        if (tid >= off) t = sm[tid - off];
        __syncthreads();
        if (tid >= off) sm[tid] += t;
        __syncthreads();
    }
    if (tid < nb) boffs[tid] = sm[tid] - v;
    if (tid == 255) offs[n] = sm[255];
}

__global__ __launch_bounds__(256) void scan3_kernel(int* __restrict__ offs,
                                                    int* __restrict__ cursor,
                                                    const int* __restrict__ boffs, int n) {
    int i = blockIdx.x * 256 + threadIdx.x;
    if (i >= n) return;
    int o = offs[i] + boffs[blockIdx.x];
    offs[i] = o;
    cursor[i] = o;
}

__global__ void fill_kernel(const int* __restrict__ ei, int* __restrict__ cursor,
                            int* __restrict__ bsrc, int E, int EP) {
    int e = blockIdx.x * blockDim.x + threadIdx.x;
    if (e >= EP) return;
    int src, dst;
    if (e < E) { src = ei[e]; dst = ei[E + e]; }
    else       { src = e - E; dst = e - E; }
    int slot = atomicAdd(&cursor[dst], 1);
    bsrc[slot] = src;
}

// ---------------- layer-1 aggregation: one wave per dst node, SINGLE PASS ----------------
__global__ __launch_bounds__(256) void agg1_kernel(const _Float16* __restrict__ h1h,
                                                   const float* __restrict__ asrc,
                                                   const float* __restrict__ adst,
                                                   const int* __restrict__ offs,
                                                   const int* __restrict__ bsrc,
                                                   const float* __restrict__ b1,
                                                   _Float16* __restrict__ h1bh) {
    int lane = threadIdx.x & 63;
    int node = blockIdx.x * 4 + (threadIdx.x >> 6);
    if (node >= N_NODES) return;
    int beg = offs[node], end = offs[node + 1];
    int hh = lane >> 3;
    float adv = adst[node * 8 + hh];

    float acc0 = 0.f, acc1 = 0.f, dsum = 0.f;
    int j = beg;
    for (; j + 2 <= end; j += 2) {
        int s0 = bsrc[j], s1 = bsrc[j + 1];
        float sa0 = asrc[s0 * 8 + hh];
        float sa1 = asrc[s1 * 8 + hh];
        f16x2 hv0 = *(const f16x2*)&h1h[(size_t)s0 * HH + 2 * lane];
        f16x2 hv1 = *(const f16x2*)&h1h[(size_t)s1 * HH + 2 * lane];
        float w0 = __expf(lrelu(sa0 + adv));
        float w1 = __expf(lrelu(sa1 + adv));
        dsum += w0 + w1;
        acc0 += w0 * (float)hv0[0] + w1 * (float)hv1[0];
        acc1 += w0 * (float)hv0[1] + w1 * (float)hv1[1];
    }
    if (j < end) {
        int s0 = bsrc[j];
        float sa0 = asrc[s0 * 8 + hh];
        f16x2 hv0 = *(const f16x2*)&h1h[(size_t)s0 * HH + 2 * lane];
        float w0 = __expf(lrelu(sa0 + adv));
        dsum += w0;
        acc0 += w0 * (float)hv0[0];
        acc1 += w0 * (float)hv0[1];
    }
    float rv = 1.f / (dsum + 1e-16f);
    float2 bv = *(const float2*)&b1[2 * lane];
    float v0 = acc0 * rv + bv.x;
    float v1 = acc1 * rv + bv.y;
    v0 = v0 > 0.f ? v0 : __expf(v0) - 1.f;   // ELU
    v1 = v1 > 0.f ? v1 : __expf(v1) - 1.f;
    f16x2 o = {(_Float16)v0, (_Float16)v1};
    *(f16x2*)&h1bh[(size_t)node * HH + 2 * lane] = o;
}

// ---------------- GEMM2: h2h[N,40] = fp16(h1bh[N,128] @ W2[128,40]) ----------------
__global__ __launch_bounds__(256) void gemm2_kernel(const _Float16* __restrict__ h1bh,
                                                    const float* __restrict__ W2,
                                                    _Float16* __restrict__ h2h) {
    __shared__ float Ws[HH * NCLS];
    for (int i = threadIdx.x; i < HH * NCLS; i += 256) Ws[i] = W2[i];
    __syncthreads();
    int idx = blockIdx.x * 256 + threadIdx.x;
    if (idx >= N_NODES * NCLS) return;
    int n = idx / NCLS, c = idx - n * NCLS;
    const f16x8* hp = (const f16x8*)&h1bh[(size_t)n * HH];
    float acc = 0.f;
#pragma unroll
    for (int k8 = 0; k8 < HH / 8; ++k8) {
        f16x8 hv = hp[k8];
#pragma unroll
        for (int i = 0; i < 8; ++i)
            acc += (float)hv[i] * Ws[(k8 * 8 + i) * NCLS + c];
    }
    h2h[idx] = (_Float16)acc;
}

__global__ void alpha2_kernel(const _Float16* __restrict__ h2h,
                              const float* __restrict__ a_src,
                              const float* __restrict__ a_dst,
                              float* __restrict__ asrc, float* __restrict__ adst) {
    int n = blockIdx.x * blockDim.x + threadIdx.x;
    if (n >= N_NODES) return;
    const f16x8* hp = (const f16x8*)&h2h[(size_t)n * NCLS];
    float s = 0.f, d = 0.f;
#pragma unroll
    for (int c8 = 0; c8 < NCLS / 8; ++c8) {
        f16x8 hv = hp[c8];
#pragma unroll
        for (int i = 0; i < 8; ++i) {
            float f = (float)hv[i];
            s += f * a_src[c8 * 8 + i];
            d += f * a_dst[c8 * 8 + i];
        }
    }
    asrc[n] = s;
    adst[n] = d;
}

// ------- layer-2 aggregation, SINGLE PASS, fused log_softmax (1 head, 40 ch) -------
__global__ __launch_bounds__(256) void agg2_kernel(const _Float16* __restrict__ h2h,
                                                   const float* __restrict__ asrc,
                                                   const float* __restrict__ adst,
                                                   const int* __restrict__ offs,
                                                   const int* __restrict__ bsrc,
                                                   const float* __restrict__ b2,
                                                   float* __restrict__ out) {
    int lane = threadIdx.x & 63;
    int node = blockIdx.x * 4 + (threadIdx.x >> 6);
    if (node >= N_NODES) return;
    int beg = offs[node], end = offs[node + 1];
    float adv = adst[node];
    bool act = lane < NCLS / 2;

    float acc0 = 0.f, acc1 = 0.f, dsum = 0.f;
    int j = beg;
    for (; j + 2 <= end; j += 2) {
        int s0 = bsrc[j], s1 = bsrc[j + 1];
        float w0 = __expf(lrelu(asrc[s0] + adv));
        float w1 = __expf(lrelu(asrc[s1] + adv));
        f16x2 hv0 = {(_Float16)0.f, (_Float16)0.f}, hv1 = hv0;
        if (act) {
            hv0 = *(const f16x2*)&h2h[(size_t)s0 * NCLS + 2 * lane];
            hv1 = *(const f16x2*)&h2h[(size_t)s1 * NCLS + 2 * lane];
        }
        dsum += w0 + w1;
        acc0 += w0 * (float)hv0[0] + w1 * (float)hv1[0];
        acc1 += w0 * (float)hv0[1] + w1 * (float)hv1[1];
    }
    if (j < end) {
        int s0 = bsrc[j];
        float w0 = __expf(lrelu(asrc[s0] + adv));
        f16x2 hv0 = {(_Float16)0.f, (_Float16)0.f};
        if (act) hv0 = *(const f16x2*)&h2h[(size_t)s0 * NCLS + 2 * lane];
        dsum += w0;
        acc0 += w0 * (float)hv0[0];
        acc1 += w0 * (float)hv0[1];
    }
    float rd = 1.f / (dsum + 1e-16f);
    float v0 = -1e30f, v1 = -1e30f;
    if (act) {
        float2 bv = *(const float2*)&b2[2 * lane];
        v0 = acc0 * rd + bv.x;
        v1 = acc1 * rd + bv.y;
    }
    float m = fmaxf(v0, v1);
#pragma unroll
    for (int o = 32; o; o >>= 1) m = fmaxf(m, __shfl_xor(m, o, 64));
    float p = act ? (__expf(v0 - m) + __expf(v1 - m)) : 0.f;
#pragma unroll
    for (int o = 32; o; o >>= 1) p += __shfl_xor(p, o, 64);
    float ls = m + __logf(p);
    if (act) {
        float2 ov = make_float2(v0 - ls, v1 - ls);
        *(float2*)&out[(size_t)node * NCLS + 2 * lane] = ov;
    }
}

extern "C" void kernel_launch(void* const* d_in, const int* in_sizes, int n_in,
                              void* d_out, int out_size, void* d_ws, size_t ws_size,
                              hipStream_t stream) {
    const float* x      = (const float*)d_in[0];
    const int*   ei     = (const int*)d_in[1];
    const float* W1     = (const float*)d_in[2];
    const float* a_src1 = (const float*)d_in[3];
    const float* a_dst1 = (const float*)d_in[4];
    const float* b1     = (const float*)d_in[5];
    const float* W2     = (const float*)d_in[6];
    const float* a_src2 = (const float*)d_in[7];
    const float* a_dst2 = (const float*)d_in[8];
    const float* b2     = (const float*)d_in[9];
    float* out = (float*)d_out;

    const int E  = in_sizes[1] / 2;
    const int EP = E + N_NODES;
    const int NB = (N_NODES + 255) / 256;

    char* w = (char*)d_ws;
    _Float16* h1h   = (_Float16*)(w + 0);          // 12,800,000 B
    _Float16* h1bh  = (_Float16*)(w + 12800000);   // 12,800,000 B
    float*    asrc1 = (float*)(w + 25600000);      //  1,600,000 B
    float*    adst1 = (float*)(w + 27200000);      //  1,600,000 B
    _Float16* h2h   = (_Float16*)(w + 28800000);   //  4,000,000 B
    float*    asrc2 = (float*)(w + 32800000);      //    200,000 B
    float*    adst2 = (float*)(w + 33000000);      //    200,000 B
    int*      deg   = (int*)(w + 33200000);        //    200,000 B
    int*      offs  = (int*)(w + 33400064);        //    200,004 B
    int*      cursor= (int*)(w + 33600128);        //    200,000 B
    int*      bsrc  = (int*)(w + 33800192);        //  3,400,000 B
    _Float16* Wt    = (_Float16*)(w + 37200256);   //    131,072 B
    int*      bsums = (int*)(w + 37331328);        //      1,024 B
    int*      boffs = (int*)(w + 37332352);        //      1,024 B (end ~37.3 MB)

    zero_int_kernel<<<(N_NODES + 255) / 256, 256, 0, stream>>>(deg, N_NODES);
    convW_kernel<<<(128 * 512 + 255) / 256, 256, 0, stream>>>(W1, Wt);
    gemm1_mfma<<<(N_NODES + 63) / 64, 256, 0, stream>>>(x, Wt, h1h);
    alpha1_kernel<<<(N_NODES * HEADS + 255) / 256, 256, 0, stream>>>(h1h, a_src1, a_dst1,
                                                                     asrc1, adst1);
    count_kernel<<<(EP + 255) / 256, 256, 0, stream>>>(ei, deg, E, EP);
    scan1_kernel<<<NB, 256, 0, stream>>>(deg, offs, bsums, N_NODES);
    scan2_kernel<<<1, 256, 0, stream>>>(bsums, boffs, NB, offs, N_NODES);
    scan3_kernel<<<NB, 256, 0, stream>>>(offs, cursor, boffs, N_NODES);
    fill_kernel<<<(EP + 255) / 256, 256, 0, stream>>>(ei, cursor, bsrc, E, EP);
    agg1_kernel<<<(N_NODES + 3) / 4, 256, 0, stream>>>(h1h, asrc1, adst1, offs, bsrc, b1, h1bh);
    gemm2_kernel<<<(N_NODES * NCLS + 255) / 256, 256, 0, stream>>>(h1bh, W2, h2h);
    alpha2_kernel<<<(N_NODES + 255) / 256, 256, 0, stream>>>(h2h, a_src2, a_dst2,
                                                             asrc2, adst2);
    agg2_kernel<<<(N_NODES + 3) / 4, 256, 0, stream>>>(h2h, asrc2, adst2, offs, bsrc, b2, out);
}